// Round 2
// baseline (501.753 us; speedup 1.0000x reference)
//
#include <hip/hip_runtime.h>

typedef __bf16 bf16x8 __attribute__((ext_vector_type(8)));
typedef float f32x4 __attribute__((ext_vector_type(4)));
typedef unsigned short u16x4 __attribute__((ext_vector_type(4)));
typedef unsigned short u16x8 __attribute__((ext_vector_type(8)));
typedef unsigned int u32x4 __attribute__((ext_vector_type(4)));

__device__ __forceinline__ float bf2f(unsigned short h) {
    union { unsigned int u; float f; } v;
    v.u = ((unsigned int)h) << 16;
    return v.f;
}
__device__ __forceinline__ unsigned short f2bf(float f) {
    union { float f; unsigned int u; } v;
    v.f = f;
    unsigned int u = v.u;
    unsigned int r = (u + 0x7FFFu + ((u >> 16) & 1u)) >> 16;
    return (unsigned short)r;
}

#define MFMA16(a, b, c) __builtin_amdgcn_mfma_f32_16x16x32_bf16((a), (b), (c), 0, 0, 0)

// ---------------------------------------------------------------------------
// fp32 -> bf16 elementwise convert (4 elems / thread)
// ---------------------------------------------------------------------------
__global__ __launch_bounds__(256) void cvt_f32_bf16(const float* __restrict__ src,
                                                    unsigned short* __restrict__ dst) {
    const int i = (blockIdx.x * 256 + threadIdx.x) * 4;
    const float4 v = *(const float4*)(src + i);
    u16x4 o;
    o[0] = f2bf(v.x); o[1] = f2bf(v.y); o[2] = f2bf(v.z); o[3] = f2bf(v.w);
    *(u16x4*)(dst + i) = o;
}

// ---------------------------------------------------------------------------
// fp32 src -> bf16 transposed dst: dst[c][r] = bf16(src[r][c])
// ---------------------------------------------------------------------------
__global__ __launch_bounds__(256) void cvt_transpose_f32(const float* __restrict__ src,
                                                         unsigned short* __restrict__ dst,
                                                         int sld, int dld) {
    __shared__ __align__(16) unsigned short tile[32][33];
    const int bx = blockIdx.x * 32;  // col base in src
    const int by = blockIdx.y * 32;  // row base in src
    const int tx = threadIdx.x;      // 0..31
    const int ty = threadIdx.y;      // 0..7
#pragma unroll
    for (int i = 0; i < 32; i += 8)
        tile[ty + i][tx] = f2bf(src[(size_t)(by + ty + i) * sld + (bx + tx)]);
    __syncthreads();
#pragma unroll
    for (int i = 0; i < 32; i += 8)
        dst[(size_t)(bx + ty + i) * dld + (by + tx)] = tile[tx][ty + i];
}

// ---------------------------------------------------------------------------
// bf16 tiled transpose: dst[c][r] = src[r][c]
// ---------------------------------------------------------------------------
__global__ __launch_bounds__(256) void transpose_bf16(const unsigned short* __restrict__ src,
                                                      unsigned short* __restrict__ dst,
                                                      int sld, int dld) {
    __shared__ __align__(16) unsigned short tile[32][33];
    const int bx = blockIdx.x * 32;
    const int by = blockIdx.y * 32;
    const int tx = threadIdx.x;
    const int ty = threadIdx.y;
#pragma unroll
    for (int i = 0; i < 32; i += 8)
        tile[ty + i][tx] = src[(size_t)(by + ty + i) * sld + (bx + tx)];
    __syncthreads();
#pragma unroll
    for (int i = 0; i < 32; i += 8)
        dst[(size_t)(bx + ty + i) * dld + (by + tx)] = tile[tx][ty + i];
}

// ---------------------------------------------------------------------------
// RoPE in-place on qkv buffer (cols 0..2559 = Q 32 heads + K 8 heads), bf16
// ---------------------------------------------------------------------------
__global__ __launch_bounds__(256) void rope_k(unsigned short* __restrict__ qkv) {
    const int idx = blockIdx.x * 256 + threadIdx.x;  // 2048 * 1280 threads
    const int s = idx / 1280;
    const int p = idx % 1280;
    const int head = p >> 5;   // 0..39 (heads 32..39 are the K heads at col 2048+)
    const int i = p & 31;      // pair index
    const size_t base = (size_t)s * 3072 + head * 64 + 2 * i;
    // inv_freq = 10000^(-2i/64) = 2^(-i * log2(10000)/32)
    const float inv = exp2f(-0.41524101186092036f * (float)i);
    const float ang = (float)s * inv;
    float sn, cs;
    __sincosf(ang, &sn, &cs);
    const float xe = bf2f(qkv[base]);
    const float xo = bf2f(qkv[base + 1]);
    qkv[base]     = f2bf(xe * cs - xo * sn);
    qkv[base + 1] = f2bf(xe * sn + xo * cs);
}

// ---------------------------------------------------------------------------
// GEMM: C[M][N] = A[M][K] @ BT[N][K]^T   (bf16 in, fp32 accum)
// out_f32: 1 -> store float32, 0 -> store bf16
// 128x128 tile / block, 4 waves 2x2, each wave 64x64 (4x4 mfma tiles), BK=64
// ---------------------------------------------------------------------------
__global__ __launch_bounds__(256) void gemm_bt(const unsigned short* __restrict__ A,
                                               const unsigned short* __restrict__ BT,
                                               void* __restrict__ Cv,
                                               int K, int lda, int ldb, int ldc,
                                               int out_f32) {
    __shared__ __align__(16) unsigned short As[128][72];
    __shared__ __align__(16) unsigned short Bs[128][72];

    const int tid = threadIdx.x;
    const int lane = tid & 63;
    const int wave = tid >> 6;
    const int quad = lane >> 4;
    const int l15 = lane & 15;
    const int bm = blockIdx.x * 128;
    const int bn = blockIdx.y * 128;
    const int wm = (wave & 1) * 64;
    const int wn = (wave >> 1) * 64;

    const int srow = tid >> 3;        // 0..31
    const int scol = (tid & 7) * 8;   // 0..56

    const unsigned short* Aptr = A + (size_t)(bm + srow) * lda + scol;
    const unsigned short* Bptr = BT + (size_t)(bn + srow) * ldb + scol;

    f32x4 acc[4][4] = {};

    for (int k0 = 0; k0 < K; k0 += 64) {
#pragma unroll
        for (int i = 0; i < 4; i++) {
            *(u32x4*)&As[srow + 32 * i][scol] = *(const u32x4*)(Aptr + (size_t)32 * i * lda + k0);
            *(u32x4*)&Bs[srow + 32 * i][scol] = *(const u32x4*)(Bptr + (size_t)32 * i * ldb + k0);
        }
        __syncthreads();
#pragma unroll
        for (int ks = 0; ks < 2; ks++) {
            bf16x8 af[4], bfr[4];
#pragma unroll
            for (int mt = 0; mt < 4; mt++)
                af[mt] = __builtin_bit_cast(bf16x8, *(const u32x4*)&As[wm + 16 * mt + l15][quad * 8 + 32 * ks]);
#pragma unroll
            for (int nt = 0; nt < 4; nt++)
                bfr[nt] = __builtin_bit_cast(bf16x8, *(const u32x4*)&Bs[wn + 16 * nt + l15][quad * 8 + 32 * ks]);
#pragma unroll
            for (int mt = 0; mt < 4; mt++)
#pragma unroll
                for (int nt = 0; nt < 4; nt++)
                    acc[mt][nt] = MFMA16(af[mt], bfr[nt], acc[mt][nt]);
        }
        __syncthreads();
    }

    // epilogue: C/D layout col = l15, row = quad*4 + r   [m89-verified]
#pragma unroll
    for (int mt = 0; mt < 4; mt++) {
#pragma unroll
        for (int nt = 0; nt < 4; nt++) {
#pragma unroll
            for (int r = 0; r < 4; r++) {
                const int row = bm + wm + 16 * mt + quad * 4 + r;
                const int col = bn + wn + 16 * nt + l15;
                if (out_f32)
                    ((float*)Cv)[(size_t)row * ldc + col] = acc[mt][nt][r];
                else
                    ((unsigned short*)Cv)[(size_t)row * ldc + col] = f2bf(acc[mt][nt][r]);
            }
        }
    }
}

// ---------------------------------------------------------------------------
// Flash attention (non-causal, GQA 4:1). Block = (q-block 64 rows, head).
// 4 waves; wave w owns q rows [16w,16w+16). Online softmax fp32.
// qkv: [2048][3072] bf16 (Q | K | V), RoPE applied to Q,K.
// vt:  [512][2048] bf16 = V^T (vt[d_global][s])
// ---------------------------------------------------------------------------
__global__ __launch_bounds__(256) void attn_kernel(const unsigned short* __restrict__ qkv,
                                                   const unsigned short* __restrict__ vt,
                                                   unsigned short* __restrict__ attn_out) {
    const int qb = blockIdx.x;
    const int h = blockIdx.y;
    const int kvh = h >> 2;
    const int tid = threadIdx.x;
    const int lane = tid & 63;
    const int wave = tid >> 6;
    const int quad = lane >> 4;
    const int l15 = lane & 15;
    const int q0 = qb * 64;

    __shared__ __align__(16) unsigned short Pl[4][16][72];

    // Q fragments (A-layout: m=l15, k=quad*8+j), pre-scaled by 1/8 (exact in bf16)
    bf16x8 qf[2];
    {
        const int qrow = q0 + wave * 16 + l15;
#pragma unroll
        for (int ks = 0; ks < 2; ks++) {
            u32x4 raw = *(const u32x4*)&qkv[(size_t)qrow * 3072 + h * 64 + quad * 8 + 32 * ks];
            u16x8 t = __builtin_bit_cast(u16x8, raw);
#pragma unroll
            for (int j = 0; j < 8; j++) t[j] = f2bf(bf2f(t[j]) * 0.125f);
            qf[ks] = __builtin_bit_cast(bf16x8, t);
        }
    }

    float m_r[4], l_r[4];
#pragma unroll
    for (int r = 0; r < 4; r++) { m_r[r] = -1e30f; l_r[r] = 0.0f; }
    f32x4 acc_o[4] = {};

    for (int kb = 0; kb < 32; kb++) {
        const int kbase = kb * 64;

        // S = Q K^T for this 64x64 tile
        f32x4 s_acc[4] = {};
#pragma unroll
        for (int n = 0; n < 4; n++) {
            const size_t krow = (size_t)(kbase + 16 * n + l15) * 3072 + 2048 + kvh * 64 + quad * 8;
            bf16x8 kf0 = __builtin_bit_cast(bf16x8, *(const u32x4*)&qkv[krow]);
            bf16x8 kf1 = __builtin_bit_cast(bf16x8, *(const u32x4*)&qkv[krow + 32]);
            s_acc[n] = MFMA16(qf[0], kf0, s_acc[n]);
            s_acc[n] = MFMA16(qf[1], kf1, s_acc[n]);
        }

        // online softmax; lane holds rows quad*4+r, cols 16n+l15
        float rmax[4];
#pragma unroll
        for (int r = 0; r < 4; r++)
            rmax[r] = fmaxf(fmaxf(s_acc[0][r], s_acc[1][r]), fmaxf(s_acc[2][r], s_acc[3][r]));
#pragma unroll
        for (int off = 1; off < 16; off <<= 1) {
#pragma unroll
            for (int r = 0; r < 4; r++)
                rmax[r] = fmaxf(rmax[r], __shfl_xor(rmax[r], off, 64));
        }

        float alpha[4], rsum[4];
#pragma unroll
        for (int r = 0; r < 4; r++) {
            const float mn = fmaxf(m_r[r], rmax[r]);
            alpha[r] = __expf(m_r[r] - mn);
            m_r[r] = mn;
            rsum[r] = 0.0f;
        }
        float p[4][4];
#pragma unroll
        for (int n = 0; n < 4; n++)
#pragma unroll
            for (int r = 0; r < 4; r++) {
                p[n][r] = __expf(s_acc[n][r] - m_r[r]);
                rsum[r] += p[n][r];
            }
#pragma unroll
        for (int off = 1; off < 16; off <<= 1) {
#pragma unroll
            for (int r = 0; r < 4; r++)
                rsum[r] += __shfl_xor(rsum[r], off, 64);
        }
#pragma unroll
        for (int r = 0; r < 4; r++) l_r[r] = alpha[r] * l_r[r] + rsum[r];
#pragma unroll
        for (int nt = 0; nt < 4; nt++)
#pragma unroll
            for (int r = 0; r < 4; r++) acc_o[nt][r] *= alpha[r];

        // P: C-layout -> LDS -> A-layout (bf16)
#pragma unroll
        for (int n = 0; n < 4; n++)
#pragma unroll
            for (int r = 0; r < 4; r++)
                Pl[wave][quad * 4 + r][16 * n + l15] = f2bf(p[n][r]);
        __syncthreads();

        bf16x8 pf0 = __builtin_bit_cast(bf16x8, *(const u32x4*)&Pl[wave][l15][quad * 8]);
        bf16x8 pf1 = __builtin_bit_cast(bf16x8, *(const u32x4*)&Pl[wave][l15][quad * 8 + 32]);

        // O += P @ V  (B-frag from vt: contiguous in k)
#pragma unroll
        for (int nt = 0; nt < 4; nt++) {
            const size_t vrow = (size_t)(kvh * 64 + 16 * nt + l15) * 2048 + kbase + quad * 8;
            bf16x8 vf0 = __builtin_bit_cast(bf16x8, *(const u32x4*)&vt[vrow]);
            bf16x8 vf1 = __builtin_bit_cast(bf16x8, *(const u32x4*)&vt[vrow + 32]);
            acc_o[nt] = MFMA16(pf0, vf0, acc_o[nt]);
            acc_o[nt] = MFMA16(pf1, vf1, acc_o[nt]);
        }
        __syncthreads();
    }

    // epilogue: divide by l, store bf16
#pragma unroll
    for (int nt = 0; nt < 4; nt++)
#pragma unroll
        for (int r = 0; r < 4; r++) {
            const float o = acc_o[nt][r] / l_r[r];
            attn_out[(size_t)(q0 + wave * 16 + quad * 4 + r) * 2048 + h * 64 + 16 * nt + l15] = f2bf(o);
        }
}

// ---------------------------------------------------------------------------
extern "C" void kernel_launch(void* const* d_in, const int* in_sizes, int n_in,
                              void* d_out, int out_size, void* d_ws, size_t ws_size,
                              hipStream_t stream) {
    (void)in_sizes; (void)n_in; (void)out_size; (void)ws_size;

    const float* X  = (const float*)d_in[0];  // 2048x2048 f32
    const float* Wq = (const float*)d_in[1];  // 2048x2048 f32
    const float* Wk = (const float*)d_in[2];  // 2048x512  f32
    const float* Wv = (const float*)d_in[3];  // 2048x512  f32
    const float* Wo = (const float*)d_in[4];  // 2048x2048 f32

    // ws layout (u16 elements), peak 10.49M u16 = 21 MB:
    //   phase 1: Xbf  [0 .. 4.19M)   wqkvT [4.19M .. 10.49M)
    //   phase 2: vt   [0 .. 1.05M)   attnO [1.05M .. 5.24M)   woT [5.24M .. 9.44M)
    // qkv (bf16 [2048][3072]) parks inside d_out (needs 12.6MB of its 16.8MB);
    // final GEMM overwrites d_out entirely with f32.
    unsigned short* ws16  = (unsigned short*)d_ws;
    unsigned short* Xbf   = ws16;
    unsigned short* wqkvT = ws16 + (size_t)4194304;
    unsigned short* qkv   = (unsigned short*)d_out;
    unsigned short* vt    = ws16;
    unsigned short* attnO = ws16 + (size_t)1048576;
    unsigned short* woT   = ws16 + (size_t)5242880;

    const dim3 tb(32, 8);

    // X -> bf16
    cvt_f32_bf16<<<4096, 256, 0, stream>>>(X, Xbf);

    // W^T (f32 -> bf16): fused [WqT | WkT | WvT] rows 0..3071
    cvt_transpose_f32<<<dim3(64, 64), tb, 0, stream>>>(Wq, wqkvT, 2048, 2048);
    cvt_transpose_f32<<<dim3(16, 64), tb, 0, stream>>>(Wk, wqkvT + (size_t)2048 * 2048, 512, 2048);
    cvt_transpose_f32<<<dim3(16, 64), tb, 0, stream>>>(Wv, wqkvT + (size_t)2560 * 2048, 512, 2048);

    // QKV = X @ [Wq|Wk|Wv]  -> bf16 in d_out
    gemm_bt<<<dim3(16, 24), 256, 0, stream>>>(Xbf, wqkvT, qkv, 2048, 2048, 2048, 3072, 0);

    // RoPE on Q and K in place
    rope_k<<<dim3((2048 * 1280) / 256), 256, 0, stream>>>(qkv);

    // V^T (V untouched by RoPE); overwrites dead Xbf region
    transpose_bf16<<<dim3(16, 64), tb, 0, stream>>>(qkv + 2560, vt, 3072, 2048);

    // Wo^T (f32 -> bf16); overwrites dead wqkvT region
    cvt_transpose_f32<<<dim3(64, 64), tb, 0, stream>>>(Wo, woT, 2048, 2048);

    // attention -> attnO (bf16)
    attn_kernel<<<dim3(32, 32), 256, 0, stream>>>(qkv, vt, attnO);

    // out = attnO @ Wo  -> f32 into d_out (overwrites dead qkv)
    gemm_bt<<<dim3(16, 16), 256, 0, stream>>>(attnO, woT, (void*)d_out, 2048, 2048, 2048, 2048, 1);
}

// Round 3
// 369.633 us; speedup vs baseline: 1.3574x; 1.3574x over previous
//
#include <hip/hip_runtime.h>

typedef __bf16 bf16x8 __attribute__((ext_vector_type(8)));
typedef float f32x4 __attribute__((ext_vector_type(4)));
typedef unsigned short u16x4 __attribute__((ext_vector_type(4)));
typedef unsigned short u16x8 __attribute__((ext_vector_type(8)));
typedef unsigned int u32x4 __attribute__((ext_vector_type(4)));

__device__ __forceinline__ float bf2f(unsigned short h) {
    union { unsigned int u; float f; } v;
    v.u = ((unsigned int)h) << 16;
    return v.f;
}
__device__ __forceinline__ unsigned short f2bf(float f) {
    return __builtin_bit_cast(unsigned short, (__bf16)f);  // native v_cvt, RNE
}
__device__ __forceinline__ bf16x8 ldg8(const unsigned short* p) {
    return __builtin_bit_cast(bf16x8, *(const u32x4*)p);
}
// async global->LDS, 16B per lane; LDS dest = wave-uniform base + lane*16
__device__ __forceinline__ void glds16(const unsigned short* g, unsigned short* l) {
    __builtin_amdgcn_global_load_lds((__attribute__((address_space(1))) void*)g,
                                     (__attribute__((address_space(3))) void*)l,
                                     16, 0, 0);
}

#define MFMA16(a, b, c) __builtin_amdgcn_mfma_f32_16x16x32_bf16((a), (b), (c), 0, 0, 0)

// ---------------------------------------------------------------------------
// fp32 -> bf16 elementwise convert (4 elems / thread)
// ---------------------------------------------------------------------------
__global__ __launch_bounds__(256) void cvt_f32_bf16(const float* __restrict__ src,
                                                    unsigned short* __restrict__ dst) {
    const int i = (blockIdx.x * 256 + threadIdx.x) * 4;
    const float4 v = *(const float4*)(src + i);
    u16x4 o;
    o[0] = f2bf(v.x); o[1] = f2bf(v.y); o[2] = f2bf(v.z); o[3] = f2bf(v.w);
    *(u16x4*)(dst + i) = o;
}

// ---------------------------------------------------------------------------
// fp32 src -> bf16 transposed dst: dst[c][r] = bf16(src[r][c])
// ---------------------------------------------------------------------------
__global__ __launch_bounds__(256) void cvt_transpose_f32(const float* __restrict__ src,
                                                         unsigned short* __restrict__ dst,
                                                         int sld, int dld) {
    __shared__ __align__(16) unsigned short tile[32][33];
    const int bx = blockIdx.x * 32;
    const int by = blockIdx.y * 32;
    const int tx = threadIdx.x;
    const int ty = threadIdx.y;
#pragma unroll
    for (int i = 0; i < 32; i += 8)
        tile[ty + i][tx] = f2bf(src[(size_t)(by + ty + i) * sld + (bx + tx)]);
    __syncthreads();
#pragma unroll
    for (int i = 0; i < 32; i += 8)
        dst[(size_t)(bx + ty + i) * dld + (by + tx)] = tile[tx][ty + i];
}

// ---------------------------------------------------------------------------
// bf16 tiled transpose: dst[c][r] = src[r][c]
// ---------------------------------------------------------------------------
__global__ __launch_bounds__(256) void transpose_bf16(const unsigned short* __restrict__ src,
                                                      unsigned short* __restrict__ dst,
                                                      int sld, int dld) {
    __shared__ __align__(16) unsigned short tile[32][33];
    const int bx = blockIdx.x * 32;
    const int by = blockIdx.y * 32;
    const int tx = threadIdx.x;
    const int ty = threadIdx.y;
#pragma unroll
    for (int i = 0; i < 32; i += 8)
        tile[ty + i][tx] = src[(size_t)(by + ty + i) * sld + (bx + tx)];
    __syncthreads();
#pragma unroll
    for (int i = 0; i < 32; i += 8)
        dst[(size_t)(bx + ty + i) * dld + (by + tx)] = tile[tx][ty + i];
}

// ---------------------------------------------------------------------------
// RoPE in-place on qkv buffer (cols 0..2559 = Q 32 heads + K 8 heads), bf16
// ---------------------------------------------------------------------------
__global__ __launch_bounds__(256) void rope_k(unsigned short* __restrict__ qkv) {
    const int idx = blockIdx.x * 256 + threadIdx.x;
    const int s = idx / 1280;
    const int p = idx % 1280;
    const int head = p >> 5;
    const int i = p & 31;
    const size_t base = (size_t)s * 3072 + head * 64 + 2 * i;
    const float inv = exp2f(-0.41524101186092036f * (float)i);
    const float ang = (float)s * inv;
    float sn, cs;
    __sincosf(ang, &sn, &cs);
    const float xe = bf2f(qkv[base]);
    const float xo = bf2f(qkv[base + 1]);
    qkv[base]     = f2bf(xe * cs - xo * sn);
    qkv[base + 1] = f2bf(xe * sn + xo * cs);
}

// ---------------------------------------------------------------------------
// GEMM: C[M][N] = A[M][K] @ BT[N][K]^T (bf16 in, fp32 accum), m97 structure:
// global_load_lds width-16 staging, XOR chunk swizzle so unpadded LDS gives
// 2-way-max (free) bank access on ds_read_b128 fragment reads.
// 128x128 tile, 4 waves 2x2, wave=64x64 (4x4 mfma), BK=64.
// ---------------------------------------------------------------------------
__global__ __launch_bounds__(256) void gemm_bt(const unsigned short* __restrict__ A,
                                               const unsigned short* __restrict__ BT,
                                               void* __restrict__ Cv,
                                               int K, int lda, int ldb, int ldc,
                                               int out_f32) {
    __shared__ __align__(16) unsigned short As[128 * 64];
    __shared__ __align__(16) unsigned short Bs[128 * 64];

    const int tid = threadIdx.x;
    const int lane = tid & 63;
    const int wave = tid >> 6;
    const int quad = lane >> 4;
    const int l15 = lane & 15;
    const int bm = blockIdx.x * 128;
    const int bn = blockIdx.y * 128;
    const int wm = (wave & 1) * 64;
    const int wn = (wave >> 1) * 64;

    // staging: call i covers rows 32i..32i+32; wave w rows 32i+8w..+8
    // lane: row_in_call = 8w + (lane>>3); chunk-slot cc = lane&7 holds global
    // chunk c = cc ^ (row&7)  (row&7 == slot row&7 since 32i,8w ≡ 0 mod 8)
    const int srow = wave * 8 + (lane >> 3);
    const int sw = (lane & 7) ^ (srow & 7);
    const unsigned short* Ag = A + (size_t)(bm + srow) * lda + sw * 8;
    const unsigned short* Bg = BT + (size_t)(bn + srow) * ldb + sw * 8;
    unsigned short* Asl = As + wave * 512;  // u16; +i*2048 per call
    unsigned short* Bsl = Bs + wave * 512;

    f32x4 acc[4][4] = {};

    for (int k0 = 0; k0 < K; k0 += 64) {
#pragma unroll
        for (int i = 0; i < 4; i++) {
            glds16(Ag + (size_t)(32 * i) * lda + k0, Asl + i * 2048);
            glds16(Bg + (size_t)(32 * i) * ldb + k0, Bsl + i * 2048);
        }
        __syncthreads();
#pragma unroll
        for (int ks = 0; ks < 2; ks++) {
            bf16x8 af[4], bfr[4];
#pragma unroll
            for (int mt = 0; mt < 4; mt++) {
                const int row = wm + 16 * mt + l15;
                af[mt] = __builtin_bit_cast(bf16x8,
                    *(const u32x4*)&As[row * 64 + (((quad + 4 * ks) ^ (row & 7)) * 8)]);
            }
#pragma unroll
            for (int nt = 0; nt < 4; nt++) {
                const int row = wn + 16 * nt + l15;
                bfr[nt] = __builtin_bit_cast(bf16x8,
                    *(const u32x4*)&Bs[row * 64 + (((quad + 4 * ks) ^ (row & 7)) * 8)]);
            }
#pragma unroll
            for (int mt = 0; mt < 4; mt++)
#pragma unroll
                for (int nt = 0; nt < 4; nt++)
                    acc[mt][nt] = MFMA16(af[mt], bfr[nt], acc[mt][nt]);
        }
        __syncthreads();
    }

    // epilogue: C/D layout col = l15, row = quad*4 + r
#pragma unroll
    for (int mt = 0; mt < 4; mt++) {
#pragma unroll
        for (int nt = 0; nt < 4; nt++) {
#pragma unroll
            for (int r = 0; r < 4; r++) {
                const int row = bm + wm + 16 * mt + quad * 4 + r;
                const int col = bn + wn + 16 * nt + l15;
                if (out_f32)
                    ((float*)Cv)[(size_t)row * ldc + col] = acc[mt][nt][r];
                else
                    ((unsigned short*)Cv)[(size_t)row * ldc + col] = f2bf(acc[mt][nt][r]);
            }
        }
    }
}

// ---------------------------------------------------------------------------
// Flash attention (non-causal, GQA 4:1). Block = (q-block 128 rows, head).
// 4 waves; wave w owns 32 q rows (2 m-tiles). NO barriers: P buffer is
// wave-private and intra-wave DS ops execute in order.
// qkv: [2048][3072] bf16 (Q|K|V, RoPE applied); vt: [512][2048] = V^T.
// ---------------------------------------------------------------------------
__global__ __launch_bounds__(256) void attn_kernel(const unsigned short* __restrict__ qkv,
                                                   const unsigned short* __restrict__ vt,
                                                   unsigned short* __restrict__ attn_out) {
    const int qb = blockIdx.x;
    const int h = blockIdx.y;
    const int kvh = h >> 2;
    const int tid = threadIdx.x;
    const int lane = tid & 63;
    const int wave = tid >> 6;
    const int quad = lane >> 4;
    const int l15 = lane & 15;
    const int w0 = qb * 128 + wave * 32;

    __shared__ __align__(16) unsigned short Pl[4][32][72];
    unsigned short (*Pw)[72] = Pl[wave];

    // Q fragments (A-layout: m=l15, k=quad*8+j), pre-scaled by 1/8 (exact)
    bf16x8 qf[2][2];
#pragma unroll
    for (int mt = 0; mt < 2; mt++)
#pragma unroll
        for (int ks = 0; ks < 2; ks++) {
            u32x4 raw = *(const u32x4*)&qkv[(size_t)(w0 + 16 * mt + l15) * 3072 + h * 64 + quad * 8 + 32 * ks];
            u16x8 t = __builtin_bit_cast(u16x8, raw);
#pragma unroll
            for (int j = 0; j < 8; j++) t[j] = f2bf(bf2f(t[j]) * 0.125f);
            qf[mt][ks] = __builtin_bit_cast(bf16x8, t);
        }

    float m_r[2][4], l_r[2][4];
#pragma unroll
    for (int mt = 0; mt < 2; mt++)
#pragma unroll
        for (int r = 0; r < 4; r++) { m_r[mt][r] = -1e30f; l_r[mt][r] = 0.0f; }
    f32x4 acc_o[2][4] = {};

    for (int kb = 0; kb < 32; kb++) {
        const int kbase = kb * 64;

        // S = Q K^T; K fragments shared across both m-tiles
        f32x4 s[2][4] = {};
#pragma unroll
        for (int n = 0; n < 4; n++) {
            const size_t krow = (size_t)(kbase + 16 * n + l15) * 3072 + 2048 + kvh * 64 + quad * 8;
            const bf16x8 kf0 = ldg8(&qkv[krow]);
            const bf16x8 kf1 = ldg8(&qkv[krow + 32]);
#pragma unroll
            for (int mt = 0; mt < 2; mt++) {
                s[mt][n] = MFMA16(qf[mt][0], kf0, s[mt][n]);
                s[mt][n] = MFMA16(qf[mt][1], kf1, s[mt][n]);
            }
        }

        // online softmax per m-tile; lane holds rows quad*4+r, cols 16n+l15
#pragma unroll
        for (int mt = 0; mt < 2; mt++) {
            float rmax[4];
#pragma unroll
            for (int r = 0; r < 4; r++)
                rmax[r] = fmaxf(fmaxf(s[mt][0][r], s[mt][1][r]), fmaxf(s[mt][2][r], s[mt][3][r]));
#pragma unroll
            for (int off = 1; off < 16; off <<= 1)
#pragma unroll
                for (int r = 0; r < 4; r++)
                    rmax[r] = fmaxf(rmax[r], __shfl_xor(rmax[r], off, 64));

            float alpha[4], rsum[4];
#pragma unroll
            for (int r = 0; r < 4; r++) {
                const float mn = fmaxf(m_r[mt][r], rmax[r]);
                alpha[r] = __expf(m_r[mt][r] - mn);
                m_r[mt][r] = mn;
                rsum[r] = 0.0f;
            }
            float p[4][4];
#pragma unroll
            for (int n = 0; n < 4; n++)
#pragma unroll
                for (int r = 0; r < 4; r++) {
                    p[n][r] = __expf(s[mt][n][r] - m_r[mt][r]);
                    rsum[r] += p[n][r];
                }
#pragma unroll
            for (int off = 1; off < 16; off <<= 1)
#pragma unroll
                for (int r = 0; r < 4; r++)
                    rsum[r] += __shfl_xor(rsum[r], off, 64);
#pragma unroll
            for (int r = 0; r < 4; r++) l_r[mt][r] = alpha[r] * l_r[mt][r] + rsum[r];
#pragma unroll
            for (int nt = 0; nt < 4; nt++)
#pragma unroll
                for (int r = 0; r < 4; r++) acc_o[mt][nt][r] *= alpha[r];

            // P: C-layout -> wave-private LDS (intra-wave in-order, no barrier)
#pragma unroll
            for (int n = 0; n < 4; n++)
#pragma unroll
                for (int r = 0; r < 4; r++)
                    Pw[16 * mt + quad * 4 + r][16 * n + l15] = f2bf(p[n][r]);
        }

        // P fragments (A-layout)
        bf16x8 pf[2][2];
#pragma unroll
        for (int mt = 0; mt < 2; mt++) {
            pf[mt][0] = __builtin_bit_cast(bf16x8, *(const u32x4*)&Pw[16 * mt + l15][quad * 8]);
            pf[mt][1] = __builtin_bit_cast(bf16x8, *(const u32x4*)&Pw[16 * mt + l15][quad * 8 + 32]);
        }

        // O += P @ V ; V fragments shared across both m-tiles
#pragma unroll
        for (int nt = 0; nt < 4; nt++) {
            const size_t vrow = (size_t)(kvh * 64 + 16 * nt + l15) * 2048 + kbase + quad * 8;
            const bf16x8 vf0 = ldg8(&vt[vrow]);
            const bf16x8 vf1 = ldg8(&vt[vrow + 32]);
#pragma unroll
            for (int mt = 0; mt < 2; mt++) {
                acc_o[mt][nt] = MFMA16(pf[mt][0], vf0, acc_o[mt][nt]);
                acc_o[mt][nt] = MFMA16(pf[mt][1], vf1, acc_o[mt][nt]);
            }
        }
    }

    // epilogue
#pragma unroll
    for (int mt = 0; mt < 2; mt++) {
        float linv[4];
#pragma unroll
        for (int r = 0; r < 4; r++) linv[r] = 1.0f / l_r[mt][r];
#pragma unroll
        for (int nt = 0; nt < 4; nt++)
#pragma unroll
            for (int r = 0; r < 4; r++)
                attn_out[(size_t)(w0 + 16 * mt + quad * 4 + r) * 2048 + h * 64 + 16 * nt + l15] =
                    f2bf(acc_o[mt][nt][r] * linv[r]);
    }
}

// ---------------------------------------------------------------------------
extern "C" void kernel_launch(void* const* d_in, const int* in_sizes, int n_in,
                              void* d_out, int out_size, void* d_ws, size_t ws_size,
                              hipStream_t stream) {
    (void)in_sizes; (void)n_in; (void)out_size; (void)ws_size;

    const float* X  = (const float*)d_in[0];
    const float* Wq = (const float*)d_in[1];
    const float* Wk = (const float*)d_in[2];
    const float* Wv = (const float*)d_in[3];
    const float* Wo = (const float*)d_in[4];

    // ws (u16): phase1 Xbf[0..4.19M) wqkvT[4.19M..10.49M)
    //           phase2 vt[0..1.05M) attnO[1.05M..5.24M) woT[5.24M..9.44M)
    // qkv parks in d_out (12.6MB of 16.8MB); final GEMM rewrites d_out in f32.
    unsigned short* ws16  = (unsigned short*)d_ws;
    unsigned short* Xbf   = ws16;
    unsigned short* wqkvT = ws16 + (size_t)4194304;
    unsigned short* qkv   = (unsigned short*)d_out;
    unsigned short* vt    = ws16;
    unsigned short* attnO = ws16 + (size_t)1048576;
    unsigned short* woT   = ws16 + (size_t)5242880;

    const dim3 tb(32, 8);

    cvt_f32_bf16<<<4096, 256, 0, stream>>>(X, Xbf);
    cvt_transpose_f32<<<dim3(64, 64), tb, 0, stream>>>(Wq, wqkvT, 2048, 2048);
    cvt_transpose_f32<<<dim3(16, 64), tb, 0, stream>>>(Wk, wqkvT + (size_t)2048 * 2048, 512, 2048);
    cvt_transpose_f32<<<dim3(16, 64), tb, 0, stream>>>(Wv, wqkvT + (size_t)2560 * 2048, 512, 2048);

    gemm_bt<<<dim3(16, 24), 256, 0, stream>>>(Xbf, wqkvT, qkv, 2048, 2048, 2048, 3072, 0);

    rope_k<<<dim3((2048 * 1280) / 256), 256, 0, stream>>>(qkv);

    transpose_bf16<<<dim3(16, 64), tb, 0, stream>>>(qkv + 2560, vt, 3072, 2048);
    cvt_transpose_f32<<<dim3(64, 64), tb, 0, stream>>>(Wo, woT, 2048, 2048);

    attn_kernel<<<dim3(16, 32), 256, 0, stream>>>(qkv, vt, attnO);

    gemm_bt<<<dim3(16, 16), 256, 0, stream>>>(attnO, woT, (void*)d_out, 2048, 2048, 2048, 2048, 1);
}

// Round 4
// 335.741 us; speedup vs baseline: 1.4945x; 1.1009x over previous
//
#include <hip/hip_runtime.h>

typedef __bf16 bf16x8 __attribute__((ext_vector_type(8)));
typedef float f32x4 __attribute__((ext_vector_type(4)));
typedef unsigned short u16x4 __attribute__((ext_vector_type(4)));
typedef unsigned short u16x8 __attribute__((ext_vector_type(8)));
typedef unsigned int u32x4 __attribute__((ext_vector_type(4)));

__device__ __forceinline__ float bf2f(unsigned short h) {
    union { unsigned int u; float f; } v;
    v.u = ((unsigned int)h) << 16;
    return v.f;
}
__device__ __forceinline__ unsigned short f2bf(float f) {
    return __builtin_bit_cast(unsigned short, (__bf16)f);  // native v_cvt, RNE
}
__device__ __forceinline__ bf16x8 ldg8(const unsigned short* p) {
    return __builtin_bit_cast(bf16x8, *(const u32x4*)p);
}
// async global->LDS, 16B per lane; LDS dest = wave-uniform base + lane*16
__device__ __forceinline__ void glds16(const unsigned short* g, unsigned short* l) {
    __builtin_amdgcn_global_load_lds((__attribute__((address_space(1))) void*)g,
                                     (__attribute__((address_space(3))) void*)l,
                                     16, 0, 0);
}

#define MFMA16(a, b, c) __builtin_amdgcn_mfma_f32_16x16x32_bf16((a), (b), (c), 0, 0, 0)

// ---------------------------------------------------------------------------
// fp32 -> bf16 elementwise convert (4 elems / thread)
// ---------------------------------------------------------------------------
__global__ __launch_bounds__(256) void cvt_f32_bf16(const float* __restrict__ src,
                                                    unsigned short* __restrict__ dst) {
    const int i = (blockIdx.x * 256 + threadIdx.x) * 4;
    const float4 v = *(const float4*)(src + i);
    u16x4 o;
    o[0] = f2bf(v.x); o[1] = f2bf(v.y); o[2] = f2bf(v.z); o[3] = f2bf(v.w);
    *(u16x4*)(dst + i) = o;
}

// ---------------------------------------------------------------------------
// Merged Wq|Wk|Wv fp32 -> bf16 transpose into wqkvT[3072][2048]
// dst[n][k] = bf16(W[k][n']); grid (kb=64, nb=96)
// ---------------------------------------------------------------------------
__global__ __launch_bounds__(256) void cvt_transpose_wqkv(const float* __restrict__ Wq,
                                                          const float* __restrict__ Wk,
                                                          const float* __restrict__ Wv,
                                                          unsigned short* __restrict__ dst) {
    const int kb = blockIdx.x * 32;
    const int nb = blockIdx.y * 32;
    const float* src; int scol; int sld;
    if (nb < 2048)      { src = Wq; scol = nb;        sld = 2048; }
    else if (nb < 2560) { src = Wk; scol = nb - 2048; sld = 512;  }
    else                { src = Wv; scol = nb - 2560; sld = 512;  }
    __shared__ __align__(16) unsigned short tile[32][33];
    const int tx = threadIdx.x;
    const int ty = threadIdx.y;
#pragma unroll
    for (int i = 0; i < 32; i += 8)
        tile[ty + i][tx] = f2bf(src[(size_t)(kb + ty + i) * sld + (scol + tx)]);
    __syncthreads();
#pragma unroll
    for (int i = 0; i < 32; i += 8)
        dst[(size_t)(nb + ty + i) * 2048 + (kb + tx)] = tile[tx][ty + i];
}

// ---------------------------------------------------------------------------
// fp32 src -> bf16 transposed dst: dst[c][r] = bf16(src[r][c])
// ---------------------------------------------------------------------------
__global__ __launch_bounds__(256) void cvt_transpose_f32(const float* __restrict__ src,
                                                         unsigned short* __restrict__ dst,
                                                         int sld, int dld) {
    __shared__ __align__(16) unsigned short tile[32][33];
    const int bx = blockIdx.x * 32;
    const int by = blockIdx.y * 32;
    const int tx = threadIdx.x;
    const int ty = threadIdx.y;
#pragma unroll
    for (int i = 0; i < 32; i += 8)
        tile[ty + i][tx] = f2bf(src[(size_t)(by + ty + i) * sld + (bx + tx)]);
    __syncthreads();
#pragma unroll
    for (int i = 0; i < 32; i += 8)
        dst[(size_t)(bx + ty + i) * dld + (by + tx)] = tile[tx][ty + i];
}

// ---------------------------------------------------------------------------
// bf16 tiled transpose: dst[c][r] = src[r][c]
// ---------------------------------------------------------------------------
__global__ __launch_bounds__(256) void transpose_bf16(const unsigned short* __restrict__ src,
                                                      unsigned short* __restrict__ dst,
                                                      int sld, int dld) {
    __shared__ __align__(16) unsigned short tile[32][33];
    const int bx = blockIdx.x * 32;
    const int by = blockIdx.y * 32;
    const int tx = threadIdx.x;
    const int ty = threadIdx.y;
#pragma unroll
    for (int i = 0; i < 32; i += 8)
        tile[ty + i][tx] = src[(size_t)(by + ty + i) * sld + (bx + tx)];
    __syncthreads();
#pragma unroll
    for (int i = 0; i < 32; i += 8)
        dst[(size_t)(bx + ty + i) * dld + (by + tx)] = tile[tx][ty + i];
}

// ---------------------------------------------------------------------------
// RoPE in-place on qkv buffer (cols 0..2559 = Q 32 heads + K 8 heads), bf16
// ---------------------------------------------------------------------------
__global__ __launch_bounds__(256) void rope_k(unsigned short* __restrict__ qkv) {
    const int idx = blockIdx.x * 256 + threadIdx.x;
    const int s = idx / 1280;
    const int p = idx % 1280;
    const int head = p >> 5;
    const int i = p & 31;
    const size_t base = (size_t)s * 3072 + head * 64 + 2 * i;
    const float inv = exp2f(-0.41524101186092036f * (float)i);
    const float ang = (float)s * inv;
    float sn, cs;
    __sincosf(ang, &sn, &cs);
    const float xe = bf2f(qkv[base]);
    const float xo = bf2f(qkv[base + 1]);
    qkv[base]     = f2bf(xe * cs - xo * sn);
    qkv[base + 1] = f2bf(xe * sn + xo * cs);
}

// ---------------------------------------------------------------------------
// GEMM: C[M][N] = A[M][K] @ BT[N][K]^T (bf16 in, fp32 accum), m97 structure:
// global_load_lds width-16 staging + XOR chunk swizzle (conflict-free b128).
// 128x128 tile, 4 waves 2x2, wave=64x64 (4x4 mfma), BK=64.
// ---------------------------------------------------------------------------
__global__ __launch_bounds__(256) void gemm_bt(const unsigned short* __restrict__ A,
                                               const unsigned short* __restrict__ BT,
                                               void* __restrict__ Cv,
                                               int K, int lda, int ldb, int ldc,
                                               int out_f32) {
    __shared__ __align__(16) unsigned short As[128 * 64];
    __shared__ __align__(16) unsigned short Bs[128 * 64];

    const int tid = threadIdx.x;
    const int lane = tid & 63;
    const int wave = tid >> 6;
    const int quad = lane >> 4;
    const int l15 = lane & 15;
    const int bm = blockIdx.x * 128;
    const int bn = blockIdx.y * 128;
    const int wm = (wave & 1) * 64;
    const int wn = (wave >> 1) * 64;

    const int srow = wave * 8 + (lane >> 3);
    const int sw = (lane & 7) ^ (srow & 7);
    const unsigned short* Ag = A + (size_t)(bm + srow) * lda + sw * 8;
    const unsigned short* Bg = BT + (size_t)(bn + srow) * ldb + sw * 8;
    unsigned short* Asl = As + wave * 512;
    unsigned short* Bsl = Bs + wave * 512;

    f32x4 acc[4][4] = {};

    for (int k0 = 0; k0 < K; k0 += 64) {
#pragma unroll
        for (int i = 0; i < 4; i++) {
            glds16(Ag + (size_t)(32 * i) * lda + k0, Asl + i * 2048);
            glds16(Bg + (size_t)(32 * i) * ldb + k0, Bsl + i * 2048);
        }
        __syncthreads();
#pragma unroll
        for (int ks = 0; ks < 2; ks++) {
            bf16x8 af[4], bfr[4];
#pragma unroll
            for (int mt = 0; mt < 4; mt++) {
                const int row = wm + 16 * mt + l15;
                af[mt] = __builtin_bit_cast(bf16x8,
                    *(const u32x4*)&As[row * 64 + (((quad + 4 * ks) ^ (row & 7)) * 8)]);
            }
#pragma unroll
            for (int nt = 0; nt < 4; nt++) {
                const int row = wn + 16 * nt + l15;
                bfr[nt] = __builtin_bit_cast(bf16x8,
                    *(const u32x4*)&Bs[row * 64 + (((quad + 4 * ks) ^ (row & 7)) * 8)]);
            }
#pragma unroll
            for (int mt = 0; mt < 4; mt++)
#pragma unroll
                for (int nt = 0; nt < 4; nt++)
                    acc[mt][nt] = MFMA16(af[mt], bfr[nt], acc[mt][nt]);
        }
        __syncthreads();
    }

    // epilogue: C/D layout col = l15, row = quad*4 + r
#pragma unroll
    for (int mt = 0; mt < 4; mt++) {
#pragma unroll
        for (int nt = 0; nt < 4; nt++) {
#pragma unroll
            for (int r = 0; r < 4; r++) {
                const int row = bm + wm + 16 * mt + quad * 4 + r;
                const int col = bn + wn + 16 * nt + l15;
                if (out_f32)
                    ((float*)Cv)[(size_t)row * ldc + col] = acc[mt][nt][r];
                else
                    ((unsigned short*)Cv)[(size_t)row * ldc + col] = f2bf(acc[mt][nt][r]);
            }
        }
    }
}

// ---------------------------------------------------------------------------
// Flash attention, fixed-max softmax + deferred row-sum. GQA 4:1.
// Block = (128 q rows, head); 4 waves, wave owns 32 q rows (2 m-tiles).
// No barriers (P buffer wave-private). Scores = q.k/8; p = exp(s - 12)
// computed as exp2(fma(s, log2e, -12*log2e)). Row sums accumulated as
// per-lane partials, single cross-lane reduce after the KV loop.
// qkv: [2048][3072] bf16 (Q|K|V, RoPE applied); vt: [512][2048] = V^T.
// ---------------------------------------------------------------------------
__global__ __launch_bounds__(256) void attn_kernel(const unsigned short* __restrict__ qkv,
                                                   const unsigned short* __restrict__ vt,
                                                   unsigned short* __restrict__ attn_out) {
    const int qb = blockIdx.x;
    const int h = blockIdx.y;
    const int kvh = h >> 2;
    const int tid = threadIdx.x;
    const int lane = tid & 63;
    const int wave = tid >> 6;
    const int quad = lane >> 4;
    const int l15 = lane & 15;
    const int w0 = qb * 128 + wave * 32;

    __shared__ __align__(16) unsigned short Pl[4][32][72];
    unsigned short (*Pw)[72] = Pl[wave];

    // Q fragments (A-layout: m=l15, k=quad*8+j), pre-scaled by 1/8 (exact)
    bf16x8 qf[2][2];
#pragma unroll
    for (int mt = 0; mt < 2; mt++)
#pragma unroll
        for (int ks = 0; ks < 2; ks++) {
            u32x4 raw = *(const u32x4*)&qkv[(size_t)(w0 + 16 * mt + l15) * 3072 + h * 64 + quad * 8 + 32 * ks];
            u16x8 t = __builtin_bit_cast(u16x8, raw);
#pragma unroll
            for (int j = 0; j < 8; j++) t[j] = f2bf(bf2f(t[j]) * 0.125f);
            qf[mt][ks] = __builtin_bit_cast(bf16x8, t);
        }

    float l_part[2][4] = {};
    f32x4 acc_o[2][4] = {};

    const float LOG2E = 1.44269504088896f;
    const float MB = -17.3123404906676f;  // -12 * log2e

    for (int kb = 0; kb < 32; kb++) {
        const int kbase = kb * 64;

        // S = Q K^T; K fragments shared across both m-tiles
        f32x4 s[2][4] = {};
#pragma unroll
        for (int n = 0; n < 4; n++) {
            const size_t krow = (size_t)(kbase + 16 * n + l15) * 3072 + 2048 + kvh * 64 + quad * 8;
            const bf16x8 kf0 = ldg8(&qkv[krow]);
            const bf16x8 kf1 = ldg8(&qkv[krow + 32]);
#pragma unroll
            for (int mt = 0; mt < 2; mt++) {
                s[mt][n] = MFMA16(qf[mt][0], kf0, s[mt][n]);
                s[mt][n] = MFMA16(qf[mt][1], kf1, s[mt][n]);
            }
        }

        // p = exp2(s*log2e - 12*log2e); accumulate per-lane partial row sums;
        // write P to wave-private LDS (C-layout rows quad*4+r, cols 16n+l15)
#pragma unroll
        for (int mt = 0; mt < 2; mt++)
#pragma unroll
            for (int n = 0; n < 4; n++)
#pragma unroll
                for (int r = 0; r < 4; r++) {
                    const float p = exp2f(fmaf(s[mt][n][r], LOG2E, MB));
                    l_part[mt][r] += p;
                    Pw[16 * mt + quad * 4 + r][16 * n + l15] = f2bf(p);
                }

        // P fragments (A-layout)
        bf16x8 pf[2][2];
#pragma unroll
        for (int mt = 0; mt < 2; mt++) {
            pf[mt][0] = __builtin_bit_cast(bf16x8, *(const u32x4*)&Pw[16 * mt + l15][quad * 8]);
            pf[mt][1] = __builtin_bit_cast(bf16x8, *(const u32x4*)&Pw[16 * mt + l15][quad * 8 + 32]);
        }

        // O += P @ V ; V fragments shared across both m-tiles
#pragma unroll
        for (int nt = 0; nt < 4; nt++) {
            const size_t vrow = (size_t)(kvh * 64 + 16 * nt + l15) * 2048 + kbase + quad * 8;
            const bf16x8 vf0 = ldg8(&vt[vrow]);
            const bf16x8 vf1 = ldg8(&vt[vrow + 32]);
#pragma unroll
            for (int mt = 0; mt < 2; mt++) {
                acc_o[mt][nt] = MFMA16(pf[mt][0], vf0, acc_o[mt][nt]);
                acc_o[mt][nt] = MFMA16(pf[mt][1], vf1, acc_o[mt][nt]);
            }
        }
    }

    // single cross-lane row-sum reduction (over the 16 l15 lanes)
#pragma unroll
    for (int off = 1; off < 16; off <<= 1)
#pragma unroll
        for (int mt = 0; mt < 2; mt++)
#pragma unroll
            for (int r = 0; r < 4; r++)
                l_part[mt][r] += __shfl_xor(l_part[mt][r], off, 64);

    // epilogue
#pragma unroll
    for (int mt = 0; mt < 2; mt++) {
        float linv[4];
#pragma unroll
        for (int r = 0; r < 4; r++) linv[r] = 1.0f / l_part[mt][r];
#pragma unroll
        for (int nt = 0; nt < 4; nt++)
#pragma unroll
            for (int r = 0; r < 4; r++)
                attn_out[(size_t)(w0 + 16 * mt + quad * 4 + r) * 2048 + h * 64 + 16 * nt + l15] =
                    f2bf(acc_o[mt][nt][r] * linv[r]);
    }
}

// ---------------------------------------------------------------------------
extern "C" void kernel_launch(void* const* d_in, const int* in_sizes, int n_in,
                              void* d_out, int out_size, void* d_ws, size_t ws_size,
                              hipStream_t stream) {
    (void)in_sizes; (void)n_in; (void)out_size; (void)ws_size;

    const float* X  = (const float*)d_in[0];
    const float* Wq = (const float*)d_in[1];
    const float* Wk = (const float*)d_in[2];
    const float* Wv = (const float*)d_in[3];
    const float* Wo = (const float*)d_in[4];

    // ws (u16): phase1 Xbf[0..4.19M) wqkvT[4.19M..10.49M)
    //           phase2 vt[0..1.05M) attnO[1.05M..5.24M) woT[5.24M..9.44M)
    // qkv parks in d_out (12.6MB of 16.8MB); final GEMM rewrites d_out in f32.
    unsigned short* ws16  = (unsigned short*)d_ws;
    unsigned short* Xbf   = ws16;
    unsigned short* wqkvT = ws16 + (size_t)4194304;
    unsigned short* qkv   = (unsigned short*)d_out;
    unsigned short* vt    = ws16;
    unsigned short* attnO = ws16 + (size_t)1048576;
    unsigned short* woT   = ws16 + (size_t)5242880;

    const dim3 tb(32, 8);

    cvt_f32_bf16<<<4096, 256, 0, stream>>>(X, Xbf);
    cvt_transpose_wqkv<<<dim3(64, 96), tb, 0, stream>>>(Wq, Wk, Wv, wqkvT);

    gemm_bt<<<dim3(16, 24), 256, 0, stream>>>(Xbf, wqkvT, qkv, 2048, 2048, 2048, 3072, 0);

    rope_k<<<dim3((2048 * 1280) / 256), 256, 0, stream>>>(qkv);

    transpose_bf16<<<dim3(16, 64), tb, 0, stream>>>(qkv + 2560, vt, 3072, 2048);
    cvt_transpose_f32<<<dim3(64, 64), tb, 0, stream>>>(Wo, woT, 2048, 2048);

    attn_kernel<<<dim3(16, 32), 256, 0, stream>>>(qkv, vt, attnO);

    gemm_bt<<<dim3(16, 16), 256, 0, stream>>>(attnO, woT, (void*)d_out, 2048, 2048, 2048, 2048, 1);
}

// Round 5
// 260.553 us; speedup vs baseline: 1.9257x; 1.2886x over previous
//
#include <hip/hip_runtime.h>

typedef __bf16 bf16x8 __attribute__((ext_vector_type(8)));
typedef float f32x4 __attribute__((ext_vector_type(4)));
typedef unsigned short u16x4 __attribute__((ext_vector_type(4)));
typedef unsigned short u16x8 __attribute__((ext_vector_type(8)));
typedef unsigned int u32x4 __attribute__((ext_vector_type(4)));

__device__ __forceinline__ float bf2f(unsigned short h) {
    union { unsigned int u; float f; } v;
    v.u = ((unsigned int)h) << 16;
    return v.f;
}
__device__ __forceinline__ unsigned short f2bf(float f) {
    return __builtin_bit_cast(unsigned short, (__bf16)f);  // native v_cvt, RNE
}
// async global->LDS, 16B per lane; LDS dest = wave-uniform base + lane*16
__device__ __forceinline__ void glds16(const unsigned short* g, unsigned short* l) {
    __builtin_amdgcn_global_load_lds((__attribute__((address_space(1))) void*)g,
                                     (__attribute__((address_space(3))) void*)l,
                                     16, 0, 0);
}

#define MFMA16(a, b, c) __builtin_amdgcn_mfma_f32_16x16x32_bf16((a), (b), (c), 0, 0, 0)

// ---------------------------------------------------------------------------
// fp32 -> bf16 elementwise convert (4 elems / thread)
// ---------------------------------------------------------------------------
__global__ __launch_bounds__(256) void cvt_f32_bf16(const float* __restrict__ src,
                                                    unsigned short* __restrict__ dst) {
    const int i = (blockIdx.x * 256 + threadIdx.x) * 4;
    const float4 v = *(const float4*)(src + i);
    u16x4 o;
    o[0] = f2bf(v.x); o[1] = f2bf(v.y); o[2] = f2bf(v.z); o[3] = f2bf(v.w);
    *(u16x4*)(dst + i) = o;
}

// ---------------------------------------------------------------------------
// Merged Wq|Wk|Wv fp32 -> bf16 transpose into wqkvT[3072][2048]
// ---------------------------------------------------------------------------
__global__ __launch_bounds__(256) void cvt_transpose_wqkv(const float* __restrict__ Wq,
                                                          const float* __restrict__ Wk,
                                                          const float* __restrict__ Wv,
                                                          unsigned short* __restrict__ dst) {
    const int kb = blockIdx.x * 32;
    const int nb = blockIdx.y * 32;
    const float* src; int scol; int sld;
    if (nb < 2048)      { src = Wq; scol = nb;        sld = 2048; }
    else if (nb < 2560) { src = Wk; scol = nb - 2048; sld = 512;  }
    else                { src = Wv; scol = nb - 2560; sld = 512;  }
    __shared__ __align__(16) unsigned short tile[32][33];
    const int tx = threadIdx.x;
    const int ty = threadIdx.y;
#pragma unroll
    for (int i = 0; i < 32; i += 8)
        tile[ty + i][tx] = f2bf(src[(size_t)(kb + ty + i) * sld + (scol + tx)]);
    __syncthreads();
#pragma unroll
    for (int i = 0; i < 32; i += 8)
        dst[(size_t)(nb + ty + i) * 2048 + (kb + tx)] = tile[tx][ty + i];
}

// ---------------------------------------------------------------------------
// fp32 src -> bf16 transposed dst
// ---------------------------------------------------------------------------
__global__ __launch_bounds__(256) void cvt_transpose_f32(const float* __restrict__ src,
                                                         unsigned short* __restrict__ dst,
                                                         int sld, int dld) {
    __shared__ __align__(16) unsigned short tile[32][33];
    const int bx = blockIdx.x * 32;
    const int by = blockIdx.y * 32;
    const int tx = threadIdx.x;
    const int ty = threadIdx.y;
#pragma unroll
    for (int i = 0; i < 32; i += 8)
        tile[ty + i][tx] = f2bf(src[(size_t)(by + ty + i) * sld + (bx + tx)]);
    __syncthreads();
#pragma unroll
    for (int i = 0; i < 32; i += 8)
        dst[(size_t)(bx + ty + i) * dld + (by + tx)] = tile[tx][ty + i];
}

// ---------------------------------------------------------------------------
// bf16 tiled transpose
// ---------------------------------------------------------------------------
__global__ __launch_bounds__(256) void transpose_bf16(const unsigned short* __restrict__ src,
                                                      unsigned short* __restrict__ dst,
                                                      int sld, int dld) {
    __shared__ __align__(16) unsigned short tile[32][33];
    const int bx = blockIdx.x * 32;
    const int by = blockIdx.y * 32;
    const int tx = threadIdx.x;
    const int ty = threadIdx.y;
#pragma unroll
    for (int i = 0; i < 32; i += 8)
        tile[ty + i][tx] = src[(size_t)(by + ty + i) * sld + (bx + tx)];
    __syncthreads();
#pragma unroll
    for (int i = 0; i < 32; i += 8)
        dst[(size_t)(bx + ty + i) * dld + (by + tx)] = tile[tx][ty + i];
}

// ---------------------------------------------------------------------------
// RoPE in-place on qkv buffer (cols 0..2559 = Q 32 heads + K 8 heads), bf16
// ---------------------------------------------------------------------------
__global__ __launch_bounds__(256) void rope_k(unsigned short* __restrict__ qkv) {
    const int idx = blockIdx.x * 256 + threadIdx.x;
    const int s = idx / 1280;
    const int p = idx % 1280;
    const int head = p >> 5;
    const int i = p & 31;
    const size_t base = (size_t)s * 3072 + head * 64 + 2 * i;
    const float inv = exp2f(-0.41524101186092036f * (float)i);
    const float ang = (float)s * inv;
    float sn, cs;
    __sincosf(ang, &sn, &cs);
    const float xe = bf2f(qkv[base]);
    const float xo = bf2f(qkv[base + 1]);
    qkv[base]     = f2bf(xe * cs - xo * sn);
    qkv[base + 1] = f2bf(xe * sn + xo * cs);
}

// ---------------------------------------------------------------------------
// GEMM: C[M][N] = A[M][K] @ BT[N][K]^T (bf16 in, fp32 accum), m97 structure.
// Tile BM x 128, 4 waves 2x2; wave = (BM/2) x 64 => BM/32 x 4 mfma tiles.
// global_load_lds width-16 staging + XOR chunk swizzle, BK=64.
// ---------------------------------------------------------------------------
template <int BM>
__global__ __launch_bounds__(256) void gemm_bt(const unsigned short* __restrict__ A,
                                               const unsigned short* __restrict__ BT,
                                               void* __restrict__ Cv,
                                               int K, int lda, int ldb, int ldc,
                                               int out_f32) {
    constexpr int MT = BM / 32;  // 16-row m-tiles per wave
    __shared__ __align__(16) unsigned short As[BM * 64];
    __shared__ __align__(16) unsigned short Bs[128 * 64];

    const int tid = threadIdx.x;
    const int lane = tid & 63;
    const int wave = tid >> 6;
    const int quad = lane >> 4;
    const int l15 = lane & 15;
    const int bm = blockIdx.x * BM;
    const int bn = blockIdx.y * 128;
    const int wm = (wave & 1) * (BM / 2);
    const int wn = (wave >> 1) * 64;

    const int srow = wave * 8 + (lane >> 3);
    const int sw = (lane & 7) ^ (srow & 7);
    const unsigned short* Ag = A + (size_t)(bm + srow) * lda + sw * 8;
    const unsigned short* Bg = BT + (size_t)(bn + srow) * ldb + sw * 8;
    unsigned short* Asl = As + wave * 512;
    unsigned short* Bsl = Bs + wave * 512;

    f32x4 acc[MT][4] = {};

    for (int k0 = 0; k0 < K; k0 += 64) {
#pragma unroll
        for (int i = 0; i < MT; i++)
            glds16(Ag + (size_t)(32 * i) * lda + k0, Asl + i * 2048);
#pragma unroll
        for (int i = 0; i < 4; i++)
            glds16(Bg + (size_t)(32 * i) * ldb + k0, Bsl + i * 2048);
        __syncthreads();
#pragma unroll
        for (int ks = 0; ks < 2; ks++) {
            bf16x8 af[MT], bfr[4];
#pragma unroll
            for (int mt = 0; mt < MT; mt++) {
                const int row = wm + 16 * mt + l15;
                af[mt] = __builtin_bit_cast(bf16x8,
                    *(const u32x4*)&As[row * 64 + (((quad + 4 * ks) ^ (row & 7)) * 8)]);
            }
#pragma unroll
            for (int nt = 0; nt < 4; nt++) {
                const int row = wn + 16 * nt + l15;
                bfr[nt] = __builtin_bit_cast(bf16x8,
                    *(const u32x4*)&Bs[row * 64 + (((quad + 4 * ks) ^ (row & 7)) * 8)]);
            }
#pragma unroll
            for (int mt = 0; mt < MT; mt++)
#pragma unroll
                for (int nt = 0; nt < 4; nt++)
                    acc[mt][nt] = MFMA16(af[mt], bfr[nt], acc[mt][nt]);
        }
        __syncthreads();
    }

    // epilogue: C/D layout col = l15, row = quad*4 + r
#pragma unroll
    for (int mt = 0; mt < MT; mt++) {
#pragma unroll
        for (int nt = 0; nt < 4; nt++) {
#pragma unroll
            for (int r = 0; r < 4; r++) {
                const int row = bm + wm + 16 * mt + quad * 4 + r;
                const int col = bn + wn + 16 * nt + l15;
                if (out_f32)
                    ((float*)Cv)[(size_t)row * ldc + col] = acc[mt][nt][r];
                else
                    ((unsigned short*)Cv)[(size_t)row * ldc + col] = f2bf(acc[mt][nt][r]);
            }
        }
    }
}

// ---------------------------------------------------------------------------
// Flash attention, fixed-max softmax + deferred row-sum + LDS-staged K/V.
// Block = (128 q rows, head); 4 waves, wave owns 32 q rows (2 m-tiles).
// Per KV-iter: stage K 64x64 tile and V^T 64x64 tile to LDS via coalesced
// global_load_lds (XOR-swizzled), barrier, compute, barrier.
// qkv: [2048][3072] bf16 (Q|K|V, RoPE applied); vt: [512][2048] = V^T.
// ---------------------------------------------------------------------------
__global__ __launch_bounds__(256) void attn_kernel(const unsigned short* __restrict__ qkv,
                                                   const unsigned short* __restrict__ vt,
                                                   unsigned short* __restrict__ attn_out) {
    const int qb = blockIdx.x;
    const int h = blockIdx.y;
    const int kvh = h >> 2;
    const int tid = threadIdx.x;
    const int lane = tid & 63;
    const int wave = tid >> 6;
    const int quad = lane >> 4;
    const int l15 = lane & 15;
    const int w0 = qb * 128 + wave * 32;

    __shared__ __align__(16) unsigned short Ks[64 * 64];
    __shared__ __align__(16) unsigned short Vs[64 * 64];
    __shared__ __align__(16) unsigned short Pl[4][32][72];
    unsigned short (*Pw)[72] = Pl[wave];

    // staging map: srow 0..31 (+32i), chunk-slot cc = lane&7 holds global
    // chunk sw = cc ^ (srow&7); lds slot = wave*512 + lane*8 (u16)
    const int srow = wave * 8 + (lane >> 3);
    const int sw = (lane & 7) ^ (srow & 7);
    const unsigned short* Kg = qkv + 2048 + kvh * 64 + sw * 8;   // + (kbase+row)*3072
    const unsigned short* Vg = vt + (size_t)(kvh * 64 + srow) * 2048 + sw * 8;  // + kbase
    unsigned short* Ksl = Ks + wave * 512;
    unsigned short* Vsl = Vs + wave * 512;

    // Q fragments (A-layout: m=l15, k=quad*8+j), pre-scaled by 1/8 (exact)
    bf16x8 qf[2][2];
#pragma unroll
    for (int mt = 0; mt < 2; mt++)
#pragma unroll
        for (int ks = 0; ks < 2; ks++) {
            u32x4 raw = *(const u32x4*)&qkv[(size_t)(w0 + 16 * mt + l15) * 3072 + h * 64 + quad * 8 + 32 * ks];
            u16x8 t = __builtin_bit_cast(u16x8, raw);
#pragma unroll
            for (int j = 0; j < 8; j++) t[j] = f2bf(bf2f(t[j]) * 0.125f);
            qf[mt][ks] = __builtin_bit_cast(bf16x8, t);
        }

    float l_part[2][4] = {};
    f32x4 acc_o[2][4] = {};

    const float LOG2E = 1.44269504088896f;
    const float MB = -17.3123404906676f;  // -12 * log2e

    for (int kb = 0; kb < 32; kb++) {
        const int kbase = kb * 64;

        // stage K tile (rows kbase..kbase+63, cols kvh*64..+64) and
        // V^T tile (rows kvh*64..+64, cols kbase..+64)
#pragma unroll
        for (int i = 0; i < 2; i++) {
            glds16(Kg + (size_t)(kbase + srow + 32 * i) * 3072, Ksl + i * 2048);
            glds16(Vg + (size_t)(32 * i) * 2048 + kbase, Vsl + i * 2048);
        }
        __syncthreads();

        // S = Q K^T; K fragments from LDS, shared across both m-tiles
        f32x4 s[2][4] = {};
#pragma unroll
        for (int n = 0; n < 4; n++) {
            const int row = 16 * n + l15;
            const bf16x8 kf0 = __builtin_bit_cast(bf16x8,
                *(const u32x4*)&Ks[row * 64 + ((quad ^ (l15 & 7)) * 8)]);
            const bf16x8 kf1 = __builtin_bit_cast(bf16x8,
                *(const u32x4*)&Ks[row * 64 + (((quad + 4) ^ (l15 & 7)) * 8)]);
#pragma unroll
            for (int mt = 0; mt < 2; mt++) {
                s[mt][n] = MFMA16(qf[mt][0], kf0, s[mt][n]);
                s[mt][n] = MFMA16(qf[mt][1], kf1, s[mt][n]);
            }
        }

        // p = exp2(s*log2e - 12*log2e); per-lane partial row sums;
        // P -> wave-private LDS (C-layout rows quad*4+r, cols 16n+l15)
#pragma unroll
        for (int mt = 0; mt < 2; mt++)
#pragma unroll
            for (int n = 0; n < 4; n++)
#pragma unroll
                for (int r = 0; r < 4; r++) {
                    const float p = exp2f(fmaf(s[mt][n][r], LOG2E, MB));
                    l_part[mt][r] += p;
                    Pw[16 * mt + quad * 4 + r][16 * n + l15] = f2bf(p);
                }

        // P fragments (A-layout)
        bf16x8 pf[2][2];
#pragma unroll
        for (int mt = 0; mt < 2; mt++) {
            pf[mt][0] = __builtin_bit_cast(bf16x8, *(const u32x4*)&Pw[16 * mt + l15][quad * 8]);
            pf[mt][1] = __builtin_bit_cast(bf16x8, *(const u32x4*)&Pw[16 * mt + l15][quad * 8 + 32]);
        }

        // O += P @ V ; V fragments from LDS, shared across both m-tiles
#pragma unroll
        for (int nt = 0; nt < 4; nt++) {
            const int row = 16 * nt + l15;
            const bf16x8 vf0 = __builtin_bit_cast(bf16x8,
                *(const u32x4*)&Vs[row * 64 + ((quad ^ (l15 & 7)) * 8)]);
            const bf16x8 vf1 = __builtin_bit_cast(bf16x8,
                *(const u32x4*)&Vs[row * 64 + (((quad + 4) ^ (l15 & 7)) * 8)]);
#pragma unroll
            for (int mt = 0; mt < 2; mt++) {
                acc_o[mt][nt] = MFMA16(pf[mt][0], vf0, acc_o[mt][nt]);
                acc_o[mt][nt] = MFMA16(pf[mt][1], vf1, acc_o[mt][nt]);
            }
        }
        __syncthreads();
    }

    // single cross-lane row-sum reduction (over the 16 l15 lanes)
#pragma unroll
    for (int off = 1; off < 16; off <<= 1)
#pragma unroll
        for (int mt = 0; mt < 2; mt++)
#pragma unroll
            for (int r = 0; r < 4; r++)
                l_part[mt][r] += __shfl_xor(l_part[mt][r], off, 64);

    // epilogue
#pragma unroll
    for (int mt = 0; mt < 2; mt++) {
        float linv[4];
#pragma unroll
        for (int r = 0; r < 4; r++) linv[r] = 1.0f / l_part[mt][r];
#pragma unroll
        for (int nt = 0; nt < 4; nt++)
#pragma unroll
            for (int r = 0; r < 4; r++)
                attn_out[(size_t)(w0 + 16 * mt + quad * 4 + r) * 2048 + h * 64 + 16 * nt + l15] =
                    f2bf(acc_o[mt][nt][r] * linv[r]);
    }
}

// ---------------------------------------------------------------------------
extern "C" void kernel_launch(void* const* d_in, const int* in_sizes, int n_in,
                              void* d_out, int out_size, void* d_ws, size_t ws_size,
                              hipStream_t stream) {
    (void)in_sizes; (void)n_in; (void)out_size; (void)ws_size;

    const float* X  = (const float*)d_in[0];
    const float* Wq = (const float*)d_in[1];
    const float* Wk = (const float*)d_in[2];
    const float* Wv = (const float*)d_in[3];
    const float* Wo = (const float*)d_in[4];

    // ws (u16): phase1 Xbf[0..4.19M) wqkvT[4.19M..10.49M)
    //           phase2 vt[0..1.05M) attnO[1.05M..5.24M) woT[5.24M..9.44M)
    // qkv parks in d_out (12.6MB of 16.8MB); final GEMM rewrites d_out in f32.
    unsigned short* ws16  = (unsigned short*)d_ws;
    unsigned short* Xbf   = ws16;
    unsigned short* wqkvT = ws16 + (size_t)4194304;
    unsigned short* qkv   = (unsigned short*)d_out;
    unsigned short* vt    = ws16;
    unsigned short* attnO = ws16 + (size_t)1048576;
    unsigned short* woT   = ws16 + (size_t)5242880;

    const dim3 tb(32, 8);

    cvt_f32_bf16<<<4096, 256, 0, stream>>>(X, Xbf);
    cvt_transpose_wqkv<<<dim3(64, 96), tb, 0, stream>>>(Wq, Wk, Wv, wqkvT);

    // QKV = X @ [Wq|Wk|Wv] -> bf16 in d_out   (64x128 tiles: 768 blocks)
    gemm_bt<64><<<dim3(32, 24), 256, 0, stream>>>(Xbf, wqkvT, qkv, 2048, 2048, 2048, 3072, 0);

    rope_k<<<dim3((2048 * 1280) / 256), 256, 0, stream>>>(qkv);

    transpose_bf16<<<dim3(16, 64), tb, 0, stream>>>(qkv + 2560, vt, 3072, 2048);
    cvt_transpose_f32<<<dim3(64, 64), tb, 0, stream>>>(Wo, woT, 2048, 2048);

    attn_kernel<<<dim3(16, 32), 256, 0, stream>>>(qkv, vt, attnO);

    // out = attnO @ Wo -> f32 into d_out   (64x128 tiles: 512 blocks)
    gemm_bt<64><<<dim3(32, 16), 256, 0, stream>>>(attnO, woT, (void*)d_out, 2048, 2048, 2048, 2048, 1);
}

// Round 6
// 242.629 us; speedup vs baseline: 2.0680x; 1.0739x over previous
//
#include <hip/hip_runtime.h>

typedef __bf16 bf16x8 __attribute__((ext_vector_type(8)));
typedef float f32x4 __attribute__((ext_vector_type(4)));
typedef unsigned short u16x4 __attribute__((ext_vector_type(4)));
typedef unsigned short u16x8 __attribute__((ext_vector_type(8)));
typedef unsigned int u32x4 __attribute__((ext_vector_type(4)));

__device__ __forceinline__ float bf2f(unsigned short h) {
    union { unsigned int u; float f; } v;
    v.u = ((unsigned int)h) << 16;
    return v.f;
}
__device__ __forceinline__ unsigned short f2bf(float f) {
    return __builtin_bit_cast(unsigned short, (__bf16)f);  // native v_cvt, RNE
}
// async global->LDS, 16B per lane; LDS dest = wave-uniform base + lane*16
__device__ __forceinline__ void glds16(const unsigned short* g, unsigned short* l) {
    __builtin_amdgcn_global_load_lds((__attribute__((address_space(1))) void*)g,
                                     (__attribute__((address_space(3))) void*)l,
                                     16, 0, 0);
}

#define MFMA16(a, b, c) __builtin_amdgcn_mfma_f32_16x16x32_bf16((a), (b), (c), 0, 0, 0)

// ---------------------------------------------------------------------------
// prep1: X f32->bf16 cvt (blocks 0..4095) + merged Wq|Wk|Wv f32->bf16
// transpose into wqkvT[3072][2048] (blocks 4096..10239)
// ---------------------------------------------------------------------------
__global__ __launch_bounds__(256) void prep1(const float* __restrict__ X,
                                             const float* __restrict__ Wq,
                                             const float* __restrict__ Wk,
                                             const float* __restrict__ Wv,
                                             unsigned short* __restrict__ Xbf,
                                             unsigned short* __restrict__ wqkvT) {
    const int b = blockIdx.x;
    const int tid = threadIdx.x;
    if (b < 4096) {
        const int i = (b * 256 + tid) * 4;
        const float4 v = *(const float4*)(X + i);
        u16x4 o;
        o[0] = f2bf(v.x); o[1] = f2bf(v.y); o[2] = f2bf(v.z); o[3] = f2bf(v.w);
        *(u16x4*)(Xbf + i) = o;
        return;
    }
    __shared__ __align__(16) unsigned short tile[32][33];
    const int tx = tid & 31, ty = tid >> 5;
    const int b2 = b - 4096;
    const int kb = (b2 & 63) * 32;   // k-dim base (rows of W)
    const int nb = (b2 >> 6) * 32;   // fused out-col base 0..3071
    const float* src; int scol, sld;
    if (nb < 2048)      { src = Wq; scol = nb;        sld = 2048; }
    else if (nb < 2560) { src = Wk; scol = nb - 2048; sld = 512;  }
    else                { src = Wv; scol = nb - 2560; sld = 512;  }
#pragma unroll
    for (int i = 0; i < 32; i += 8)
        tile[ty + i][tx] = f2bf(src[(size_t)(kb + ty + i) * sld + (scol + tx)]);
    __syncthreads();
#pragma unroll
    for (int i = 0; i < 32; i += 8)
        wqkvT[(size_t)(nb + ty + i) * 2048 + (kb + tx)] = tile[tx][ty + i];
}

// ---------------------------------------------------------------------------
// prep2 (post-QKV GEMM): Wo f32->bf16 transpose -> woT (blocks 0..4095)
// + V bf16 transpose qkv[:,2560:3072] -> vt[512][2048] (blocks 4096..5119)
// ---------------------------------------------------------------------------
__global__ __launch_bounds__(256) void prep2(const float* __restrict__ Wo,
                                             const unsigned short* __restrict__ qkv,
                                             unsigned short* __restrict__ woT,
                                             unsigned short* __restrict__ vt) {
    const int b = blockIdx.x;
    const int tid = threadIdx.x;
    const int tx = tid & 31, ty = tid >> 5;
    __shared__ __align__(16) unsigned short tile[32][33];
    if (b < 4096) {
        const int kb = (b & 63) * 32;
        const int nb = (b >> 6) * 32;
#pragma unroll
        for (int i = 0; i < 32; i += 8)
            tile[ty + i][tx] = f2bf(Wo[(size_t)(kb + ty + i) * 2048 + (nb + tx)]);
        __syncthreads();
#pragma unroll
        for (int i = 0; i < 32; i += 8)
            woT[(size_t)(nb + ty + i) * 2048 + (kb + tx)] = tile[tx][ty + i];
    } else {
        const int b2 = b - 4096;
        const int bx = (b2 & 15) * 32;   // d-col base in V (0..511)
        const int by = (b2 >> 4) * 32;   // s-row base (0..2047)
#pragma unroll
        for (int i = 0; i < 32; i += 8)
            tile[ty + i][tx] = qkv[(size_t)(by + ty + i) * 3072 + 2560 + bx + tx];
        __syncthreads();
#pragma unroll
        for (int i = 0; i < 32; i += 8)
            vt[(size_t)(bx + ty + i) * 2048 + (by + tx)] = tile[tx][ty + i];
    }
}

// ---------------------------------------------------------------------------
// GEMM: C[M][N] = A[M][K] @ BT[N][K]^T (bf16 in, fp32 accum), m97 structure.
// Tile BM x 128, 4 waves 2x2; global_load_lds width-16 + XOR chunk swizzle.
// ROPE: apply rotary embedding in epilogue for cols < 2560 (QKV GEMM).
// ---------------------------------------------------------------------------
template <int BM, bool ROPE>
__global__ __launch_bounds__(256) void gemm_bt(const unsigned short* __restrict__ A,
                                               const unsigned short* __restrict__ BT,
                                               void* __restrict__ Cv,
                                               int K, int lda, int ldb, int ldc,
                                               int out_f32) {
    constexpr int MT = BM / 32;
    __shared__ __align__(16) unsigned short As[BM * 64];
    __shared__ __align__(16) unsigned short Bs[128 * 64];

    const int tid = threadIdx.x;
    const int lane = tid & 63;
    const int wave = tid >> 6;
    const int quad = lane >> 4;
    const int l15 = lane & 15;
    const int bm = blockIdx.x * BM;
    const int bn = blockIdx.y * 128;
    const int wm = (wave & 1) * (BM / 2);
    const int wn = (wave >> 1) * 64;

    const int srow = wave * 8 + (lane >> 3);
    const int sw = (lane & 7) ^ (srow & 7);
    const unsigned short* Ag = A + (size_t)(bm + srow) * lda + sw * 8;
    const unsigned short* Bg = BT + (size_t)(bn + srow) * ldb + sw * 8;
    unsigned short* Asl = As + wave * 512;
    unsigned short* Bsl = Bs + wave * 512;

    f32x4 acc[MT][4] = {};

    for (int k0 = 0; k0 < K; k0 += 64) {
#pragma unroll
        for (int i = 0; i < MT; i++)
            glds16(Ag + (size_t)(32 * i) * lda + k0, Asl + i * 2048);
#pragma unroll
        for (int i = 0; i < 4; i++)
            glds16(Bg + (size_t)(32 * i) * ldb + k0, Bsl + i * 2048);
        __syncthreads();
#pragma unroll
        for (int ks = 0; ks < 2; ks++) {
            bf16x8 af[MT], bfr[4];
#pragma unroll
            for (int mt = 0; mt < MT; mt++) {
                const int row = wm + 16 * mt + l15;
                af[mt] = __builtin_bit_cast(bf16x8,
                    *(const u32x4*)&As[row * 64 + (((quad + 4 * ks) ^ (row & 7)) * 8)]);
            }
#pragma unroll
            for (int nt = 0; nt < 4; nt++) {
                const int row = wn + 16 * nt + l15;
                bfr[nt] = __builtin_bit_cast(bf16x8,
                    *(const u32x4*)&Bs[row * 64 + (((quad + 4 * ks) ^ (row & 7)) * 8)]);
            }
#pragma unroll
            for (int mt = 0; mt < MT; mt++)
#pragma unroll
                for (int nt = 0; nt < 4; nt++)
                    acc[mt][nt] = MFMA16(af[mt], bfr[nt], acc[mt][nt]);
        }
        __syncthreads();
    }

    // fused RoPE on fp32 accumulators (cols < 2560 = Q|K), pairwise via shfl
    if (ROPE) {
#pragma unroll
        for (int mt = 0; mt < MT; mt++) {
#pragma unroll
            for (int nt = 0; nt < 4; nt++) {
                const int col = bn + wn + 16 * nt + l15;
                if (col < 2560) {  // 16-aligned boundary -> wave-uniform branch
                    const int i = (col & 63) >> 1;
                    const float inv = exp2f(-0.41524101186092036f * (float)i);
                    const float sign = (col & 1) ? 1.0f : -1.0f;
#pragma unroll
                    for (int r = 0; r < 4; r++) {
                        const int row = bm + wm + 16 * mt + quad * 4 + r;
                        float sn, cs;
                        __sincosf((float)row * inv, &sn, &cs);
                        const float partner = __shfl_xor(acc[mt][nt][r], 1, 64);
                        acc[mt][nt][r] = acc[mt][nt][r] * cs + sign * partner * sn;
                    }
                }
            }
        }
    }

    // epilogue: C/D layout col = l15, row = quad*4 + r
#pragma unroll
    for (int mt = 0; mt < MT; mt++) {
#pragma unroll
        for (int nt = 0; nt < 4; nt++) {
#pragma unroll
            for (int r = 0; r < 4; r++) {
                const int row = bm + wm + 16 * mt + quad * 4 + r;
                const int col = bn + wn + 16 * nt + l15;
                if (out_f32)
                    ((float*)Cv)[(size_t)row * ldc + col] = acc[mt][nt][r];
                else
                    ((unsigned short*)Cv)[(size_t)row * ldc + col] = f2bf(acc[mt][nt][r]);
            }
        }
    }
}

// ---------------------------------------------------------------------------
// Flash attention, S^T-trick + fixed-max softmax + deferred row-sum.
// Block = (128 q rows, head); 4 waves, wave owns 32 q rows (2 m-tiles).
// BK=128 KV staging (2 barriers per 128 kv). S^T = MFMA(kf, qf) puts each
// lane's 4 P values contiguous in kv -> ds_write_b64 P-store, b128 reads.
// qkv: [2048][3072] bf16 (Q|K|V, RoPE applied); vt: [512][2048] = V^T.
// ---------------------------------------------------------------------------
__global__ __launch_bounds__(256) void attn_kernel(const unsigned short* __restrict__ qkv,
                                                   const unsigned short* __restrict__ vt,
                                                   unsigned short* __restrict__ attn_out) {
    const int qb = blockIdx.x;
    const int h = blockIdx.y;
    const int kvh = h >> 2;
    const int tid = threadIdx.x;
    const int lane = tid & 63;
    const int wave = tid >> 6;
    const int quad = lane >> 4;
    const int l15 = lane & 15;
    const int w0 = qb * 128 + wave * 32;

    __shared__ __align__(16) unsigned short Ks[128 * 64];   // K rows x 64 d
    __shared__ __align__(16) unsigned short Vs[64 * 128];   // V^T: 64 d x 128 kv
    __shared__ __align__(16) unsigned short St[4][32][72];  // per-wave P (q x kv)
    unsigned short (*Sw)[72] = St[wave];

    // K staging map (64-u16 rows, 8 chunk slots)
    const int srow = wave * 8 + (lane >> 3);
    const int swK = (lane & 7) ^ (srow & 7);
    const unsigned short* Kg = qkv + 2048 + kvh * 64 + swK * 8;  // + (kbase+srow+32i)*3072
    unsigned short* Ksl = Ks + wave * 512;
    // V staging map (128-u16 rows, 16 chunk slots)
    const int vrow = wave * 4 + (lane >> 4);
    const int swV = (lane & 15) ^ (vrow & 7);
    const unsigned short* Vg = vt + (size_t)(kvh * 64 + vrow) * 2048 + swV * 8;  // + 16i*2048 + kbase
    unsigned short* Vsl = Vs + wave * 512;

    // Q fragments (MFMA B-operand: n=q=l15, k=quad*8+j), pre-scaled by 1/8
    bf16x8 qf[2][2];
#pragma unroll
    for (int mt = 0; mt < 2; mt++)
#pragma unroll
        for (int ks = 0; ks < 2; ks++) {
            u32x4 raw = *(const u32x4*)&qkv[(size_t)(w0 + 16 * mt + l15) * 3072 + h * 64 + quad * 8 + 32 * ks];
            u16x8 t = __builtin_bit_cast(u16x8, raw);
#pragma unroll
            for (int j = 0; j < 8; j++) t[j] = f2bf(bf2f(t[j]) * 0.125f);
            qf[mt][ks] = __builtin_bit_cast(bf16x8, t);
        }

    float l_part[2] = {};
    f32x4 acc_o[2][4] = {};

    const float LOG2E = 1.44269504088896f;
    const float MB = -17.3123404906676f;  // -12 * log2e

    for (int kb2 = 0; kb2 < 16; kb2++) {
        const int kbase = kb2 * 128;
#pragma unroll
        for (int i = 0; i < 4; i++) {
            glds16(Kg + (size_t)(kbase + srow + 32 * i) * 3072, Ksl + i * 2048);
            glds16(Vg + (size_t)(16 * i) * 2048 + kbase, Vsl + i * 2048);
        }
        __syncthreads();

#pragma unroll
        for (int kh = 0; kh < 2; kh++) {
            // S^T = K Q^T : A = K-frag (m=kv), B = Q-frag (n=q)
            f32x4 st[2][4] = {};
#pragma unroll
            for (int n = 0; n < 4; n++) {
                const int row = kh * 64 + 16 * n + l15;
                const bf16x8 kf0 = __builtin_bit_cast(bf16x8,
                    *(const u32x4*)&Ks[row * 64 + ((quad ^ (l15 & 7)) * 8)]);
                const bf16x8 kf1 = __builtin_bit_cast(bf16x8,
                    *(const u32x4*)&Ks[row * 64 + (((quad + 4) ^ (l15 & 7)) * 8)]);
#pragma unroll
                for (int mt = 0; mt < 2; mt++) {
                    st[mt][n] = MFMA16(kf0, qf[mt][0], st[mt][n]);
                    st[mt][n] = MFMA16(kf1, qf[mt][1], st[mt][n]);
                }
            }

            // p = exp2(s*log2e - 12*log2e); lane holds q=l15, kv=16n+quad*4+r
            // -> contiguous b64 store into Sw[q][kv]; scalar l_part per m-tile
#pragma unroll
            for (int mt = 0; mt < 2; mt++)
#pragma unroll
                for (int n = 0; n < 4; n++) {
                    u16x4 pk;
#pragma unroll
                    for (int r = 0; r < 4; r++) {
                        const float p = exp2f(fmaf(st[mt][n][r], LOG2E, MB));
                        l_part[mt] += p;
                        pk[r] = f2bf(p);
                    }
                    *(u16x4*)&Sw[16 * mt + l15][16 * n + quad * 4] = pk;
                }

            // P A-frags (m=q=l15, k=kv=quad*8+j) straight from Sw rows
            bf16x8 pf[2][2];
#pragma unroll
            for (int mt = 0; mt < 2; mt++) {
                pf[mt][0] = __builtin_bit_cast(bf16x8, *(const u32x4*)&Sw[16 * mt + l15][quad * 8]);
                pf[mt][1] = __builtin_bit_cast(bf16x8, *(const u32x4*)&Sw[16 * mt + l15][quad * 8 + 32]);
            }

            // O += P @ V : B = V^T rows (n=d=l15, k=kv)
#pragma unroll
            for (int nt = 0; nt < 4; nt++) {
                const int row = 16 * nt + l15;
                const int c0 = kh * 8 + (quad ^ (l15 & 7));
                const int c1 = kh * 8 + ((quad + 4) ^ (l15 & 7));
                const bf16x8 vf0 = __builtin_bit_cast(bf16x8, *(const u32x4*)&Vs[row * 128 + c0 * 8]);
                const bf16x8 vf1 = __builtin_bit_cast(bf16x8, *(const u32x4*)&Vs[row * 128 + c1 * 8]);
#pragma unroll
                for (int mt = 0; mt < 2; mt++) {
                    acc_o[mt][nt] = MFMA16(pf[mt][0], vf0, acc_o[mt][nt]);
                    acc_o[mt][nt] = MFMA16(pf[mt][1], vf1, acc_o[mt][nt]);
                }
            }
        }
        __syncthreads();
    }

    // reduce l_part across the 4 quads (lane holds q=l15)
#pragma unroll
    for (int mt = 0; mt < 2; mt++) {
        l_part[mt] += __shfl_xor(l_part[mt], 16, 64);
        l_part[mt] += __shfl_xor(l_part[mt], 32, 64);
    }

    // epilogue: acc_o lane layout q=quad*4+r, d=16nt+l15; fetch l via shfl
#pragma unroll
    for (int mt = 0; mt < 2; mt++) {
        float linv[4];
#pragma unroll
        for (int r = 0; r < 4; r++)
            linv[r] = 1.0f / __shfl(l_part[mt], quad * 4 + r, 64);
#pragma unroll
        for (int nt = 0; nt < 4; nt++)
#pragma unroll
            for (int r = 0; r < 4; r++)
                attn_out[(size_t)(w0 + 16 * mt + quad * 4 + r) * 2048 + h * 64 + 16 * nt + l15] =
                    f2bf(acc_o[mt][nt][r] * linv[r]);
    }
}

// ---------------------------------------------------------------------------
extern "C" void kernel_launch(void* const* d_in, const int* in_sizes, int n_in,
                              void* d_out, int out_size, void* d_ws, size_t ws_size,
                              hipStream_t stream) {
    (void)in_sizes; (void)n_in; (void)out_size; (void)ws_size;

    const float* X  = (const float*)d_in[0];
    const float* Wq = (const float*)d_in[1];
    const float* Wk = (const float*)d_in[2];
    const float* Wv = (const float*)d_in[3];
    const float* Wo = (const float*)d_in[4];

    // ws (u16): phase1 Xbf[0..4.19M) wqkvT[4.19M..10.49M)
    //           phase2 vt[0..1.05M) attnO[1.05M..5.24M) woT[5.24M..9.44M)
    // qkv parks in d_out (12.6MB of 16.8MB); final GEMM rewrites d_out in f32.
    unsigned short* ws16  = (unsigned short*)d_ws;
    unsigned short* Xbf   = ws16;
    unsigned short* wqkvT = ws16 + (size_t)4194304;
    unsigned short* qkv   = (unsigned short*)d_out;
    unsigned short* vt    = ws16;
    unsigned short* attnO = ws16 + (size_t)1048576;
    unsigned short* woT   = ws16 + (size_t)5242880;

    // X cvt + Wqkv transpose
    prep1<<<10240, 256, 0, stream>>>(X, Wq, Wk, Wv, Xbf, wqkvT);

    // QKV = X @ [Wq|Wk|Wv] -> bf16 in d_out, RoPE fused in epilogue
    gemm_bt<64, true><<<dim3(32, 24), 256, 0, stream>>>(Xbf, wqkvT, qkv, 2048, 2048, 2048, 3072, 0);

    // Wo transpose (into dead wqkvT region) + V^T (into dead Xbf region)
    prep2<<<5120, 256, 0, stream>>>(Wo, qkv, woT, vt);

    // attention -> attnO (bf16)
    attn_kernel<<<dim3(16, 32), 256, 0, stream>>>(qkv, vt, attnO);

    // out = attnO @ Wo -> f32 into d_out (overwrites dead qkv)
    gemm_bt<64, false><<<dim3(32, 16), 256, 0, stream>>>(attnO, woT, (void*)d_out, 2048, 2048, 2048, 2048, 1);
}

// Round 7
// 235.586 us; speedup vs baseline: 2.1298x; 1.0299x over previous
//
#include <hip/hip_runtime.h>

typedef __bf16 bf16x8 __attribute__((ext_vector_type(8)));
typedef float f32x4 __attribute__((ext_vector_type(4)));
typedef unsigned short u16x4 __attribute__((ext_vector_type(4)));
typedef unsigned short u16x8 __attribute__((ext_vector_type(8)));
typedef unsigned int u32x4 __attribute__((ext_vector_type(4)));

__device__ __forceinline__ float bf2f(unsigned short h) {
    union { unsigned int u; float f; } v;
    v.u = ((unsigned int)h) << 16;
    return v.f;
}
__device__ __forceinline__ unsigned short f2bf(float f) {
    return __builtin_bit_cast(unsigned short, (__bf16)f);  // native v_cvt, RNE
}
// async global->LDS, 16B per lane; LDS dest = wave-uniform base + lane*16
__device__ __forceinline__ void glds16(const unsigned short* g, unsigned short* l) {
    __builtin_amdgcn_global_load_lds((__attribute__((address_space(1))) void*)g,
                                     (__attribute__((address_space(3))) void*)l,
                                     16, 0, 0);
}

#define MFMA16(a, b, c) __builtin_amdgcn_mfma_f32_16x16x32_bf16((a), (b), (c), 0, 0, 0)

// ---------------------------------------------------------------------------
// prep1: X f32->bf16 cvt (blocks 0..4095) + merged Wq|Wk|Wv f32->bf16
// transpose into wqkvT[3072][2048] (blocks 4096..10239)
// ---------------------------------------------------------------------------
__global__ __launch_bounds__(256) void prep1(const float* __restrict__ X,
                                             const float* __restrict__ Wq,
                                             const float* __restrict__ Wk,
                                             const float* __restrict__ Wv,
                                             unsigned short* __restrict__ Xbf,
                                             unsigned short* __restrict__ wqkvT) {
    const int b = blockIdx.x;
    const int tid = threadIdx.x;
    if (b < 4096) {
        const int i = (b * 256 + tid) * 4;
        const float4 v = *(const float4*)(X + i);
        u16x4 o;
        o[0] = f2bf(v.x); o[1] = f2bf(v.y); o[2] = f2bf(v.z); o[3] = f2bf(v.w);
        *(u16x4*)(Xbf + i) = o;
        return;
    }
    __shared__ __align__(16) unsigned short tile[32][33];
    const int tx = tid & 31, ty = tid >> 5;
    const int b2 = b - 4096;
    const int kb = (b2 & 63) * 32;   // k-dim base (rows of W)
    const int nb = (b2 >> 6) * 32;   // fused out-col base 0..3071
    const float* src; int scol, sld;
    if (nb < 2048)      { src = Wq; scol = nb;        sld = 2048; }
    else if (nb < 2560) { src = Wk; scol = nb - 2048; sld = 512;  }
    else                { src = Wv; scol = nb - 2560; sld = 512;  }
#pragma unroll
    for (int i = 0; i < 32; i += 8)
        tile[ty + i][tx] = f2bf(src[(size_t)(kb + ty + i) * sld + (scol + tx)]);
    __syncthreads();
#pragma unroll
    for (int i = 0; i < 32; i += 8)
        wqkvT[(size_t)(nb + ty + i) * 2048 + (kb + tx)] = tile[tx][ty + i];
}

// ---------------------------------------------------------------------------
// prep2 (post-QKV GEMM): Wo f32->bf16 transpose -> woT (blocks 0..4095)
// + V bf16 transpose qkv[:,2560:3072] -> vt[512][2048] (blocks 4096..5119)
// ---------------------------------------------------------------------------
__global__ __launch_bounds__(256) void prep2(const float* __restrict__ Wo,
                                             const unsigned short* __restrict__ qkv,
                                             unsigned short* __restrict__ woT,
                                             unsigned short* __restrict__ vt) {
    const int b = blockIdx.x;
    const int tid = threadIdx.x;
    const int tx = tid & 31, ty = tid >> 5;
    __shared__ __align__(16) unsigned short tile[32][33];
    if (b < 4096) {
        const int kb = (b & 63) * 32;
        const int nb = (b >> 6) * 32;
#pragma unroll
        for (int i = 0; i < 32; i += 8)
            tile[ty + i][tx] = f2bf(Wo[(size_t)(kb + ty + i) * 2048 + (nb + tx)]);
        __syncthreads();
#pragma unroll
        for (int i = 0; i < 32; i += 8)
            woT[(size_t)(nb + ty + i) * 2048 + (kb + tx)] = tile[tx][ty + i];
    } else {
        const int b2 = b - 4096;
        const int bx = (b2 & 15) * 32;   // d-col base in V (0..511)
        const int by = (b2 >> 4) * 32;   // s-row base (0..2047)
#pragma unroll
        for (int i = 0; i < 32; i += 8)
            tile[ty + i][tx] = qkv[(size_t)(by + ty + i) * 3072 + 2560 + bx + tx];
        __syncthreads();
#pragma unroll
        for (int i = 0; i < 32; i += 8)
            vt[(size_t)(bx + ty + i) * 2048 + (by + tx)] = tile[tx][ty + i];
    }
}

// ---------------------------------------------------------------------------
// GEMM: C[M][N] = A[M][K] @ BT[N][K]^T (bf16 in, fp32 accum), m97 structure,
// BK=128 (half the barriers; 48KB LDS keeps 3 blocks/CU for BM=64).
// Tile BM x 128, 4 waves 2x2; global_load_lds width-16 + XOR chunk swizzle.
// ROPE: apply rotary embedding in epilogue for cols < 2560 (QKV GEMM).
// LDS row stride = 128 u16; 16 chunk-slots of 8 u16; chunk c of row r is
// stored at slot c ^ (r&7)  (global col = k0 + sw*8, sw = slot ^ (r&7)).
// ---------------------------------------------------------------------------
template <int BM, bool ROPE>
__global__ __launch_bounds__(256) void gemm_bt(const unsigned short* __restrict__ A,
                                               const unsigned short* __restrict__ BT,
                                               void* __restrict__ Cv,
                                               int K, int lda, int ldb, int ldc,
                                               int out_f32) {
    constexpr int MT = BM / 32;
    constexpr int ACALLS = BM / 16;   // 4KB-chunks for A tile
    __shared__ __align__(16) unsigned short As[BM * 128];
    __shared__ __align__(16) unsigned short Bs[128 * 128];

    const int tid = threadIdx.x;
    const int lane = tid & 63;
    const int wave = tid >> 6;
    const int quad = lane >> 4;
    const int l15 = lane & 15;
    const int bm = blockIdx.x * BM;
    const int bn = blockIdx.y * 128;
    const int wm = (wave & 1) * (BM / 2);
    const int wn = (wave >> 1) * 64;

    // staging: call i covers rows 16i..16i+16; lane row-in-call = wave*4 + (lane>>4)
    const int srow = wave * 4 + (lane >> 4);          // 0..15
    const int sw = (lane & 15) ^ (srow & 7);          // swizzled chunk 0..15
    const unsigned short* Ag = A + (size_t)(bm + srow) * lda + sw * 8;
    const unsigned short* Bg = BT + (size_t)(bn + srow) * ldb + sw * 8;
    unsigned short* Asl = As + wave * 512;            // + i*2048 per call
    unsigned short* Bsl = Bs + wave * 512;

    f32x4 acc[MT][4] = {};

    for (int k0 = 0; k0 < K; k0 += 128) {
#pragma unroll
        for (int i = 0; i < ACALLS; i++)
            glds16(Ag + (size_t)(16 * i) * lda + k0, Asl + i * 2048);
#pragma unroll
        for (int i = 0; i < 8; i++)
            glds16(Bg + (size_t)(16 * i) * ldb + k0, Bsl + i * 2048);
        __syncthreads();
#pragma unroll
        for (int ks = 0; ks < 4; ks++) {
            bf16x8 af[MT], bfr[4];
#pragma unroll
            for (int mt = 0; mt < MT; mt++) {
                const int row = wm + 16 * mt + l15;
                af[mt] = __builtin_bit_cast(bf16x8,
                    *(const u32x4*)&As[row * 128 + (((quad + 4 * ks) ^ (row & 7)) * 8)]);
            }
#pragma unroll
            for (int nt = 0; nt < 4; nt++) {
                const int row = wn + 16 * nt + l15;
                bfr[nt] = __builtin_bit_cast(bf16x8,
                    *(const u32x4*)&Bs[row * 128 + (((quad + 4 * ks) ^ (row & 7)) * 8)]);
            }
#pragma unroll
            for (int mt = 0; mt < MT; mt++)
#pragma unroll
                for (int nt = 0; nt < 4; nt++)
                    acc[mt][nt] = MFMA16(af[mt], bfr[nt], acc[mt][nt]);
        }
        __syncthreads();
    }

    // fused RoPE on fp32 accumulators (cols < 2560 = Q|K), pairwise via shfl
    if (ROPE) {
#pragma unroll
        for (int mt = 0; mt < MT; mt++) {
#pragma unroll
            for (int nt = 0; nt < 4; nt++) {
                const int col = bn + wn + 16 * nt + l15;
                if (col < 2560) {  // 16-aligned boundary -> wave-uniform branch
                    const int i = (col & 63) >> 1;
                    const float inv = exp2f(-0.41524101186092036f * (float)i);
                    const float sign = (col & 1) ? 1.0f : -1.0f;
#pragma unroll
                    for (int r = 0; r < 4; r++) {
                        const int row = bm + wm + 16 * mt + quad * 4 + r;
                        float sn, cs;
                        __sincosf((float)row * inv, &sn, &cs);
                        const float partner = __shfl_xor(acc[mt][nt][r], 1, 64);
                        acc[mt][nt][r] = acc[mt][nt][r] * cs + sign * partner * sn;
                    }
                }
            }
        }
    }

    // epilogue: C/D layout col = l15, row = quad*4 + r
#pragma unroll
    for (int mt = 0; mt < MT; mt++) {
#pragma unroll
        for (int nt = 0; nt < 4; nt++) {
#pragma unroll
            for (int r = 0; r < 4; r++) {
                const int row = bm + wm + 16 * mt + quad * 4 + r;
                const int col = bn + wn + 16 * nt + l15;
                if (out_f32)
                    ((float*)Cv)[(size_t)row * ldc + col] = acc[mt][nt][r];
                else
                    ((unsigned short*)Cv)[(size_t)row * ldc + col] = f2bf(acc[mt][nt][r]);
            }
        }
    }
}

// ---------------------------------------------------------------------------
// Flash attention, S^T-trick + fixed-max softmax + MFMA row-sum (P @ ones).
// Block = (128 q rows, head); 4 waves, wave owns 32 q rows (2 m-tiles).
// BK=128 KV staging. No per-iter shuffles or adds: row sums accumulate in
// an extra MFMA accumulator whose C-layout matches acc_o's rows exactly.
// qkv: [2048][3072] bf16 (Q|K|V, RoPE applied); vt: [512][2048] = V^T.
// ---------------------------------------------------------------------------
__global__ __launch_bounds__(256) void attn_kernel(const unsigned short* __restrict__ qkv,
                                                   const unsigned short* __restrict__ vt,
                                                   unsigned short* __restrict__ attn_out) {
    const int qb = blockIdx.x;
    const int h = blockIdx.y;
    const int kvh = h >> 2;
    const int tid = threadIdx.x;
    const int lane = tid & 63;
    const int wave = tid >> 6;
    const int quad = lane >> 4;
    const int l15 = lane & 15;
    const int w0 = qb * 128 + wave * 32;

    __shared__ __align__(16) unsigned short Ks[128 * 64];   // K rows x 64 d
    __shared__ __align__(16) unsigned short Vs[64 * 128];   // V^T: 64 d x 128 kv
    __shared__ __align__(16) unsigned short St[4][32][72];  // per-wave P (q x kv)
    unsigned short (*Sw)[72] = St[wave];

    // K staging map (64-u16 rows, 8 chunk slots)
    const int srow = wave * 8 + (lane >> 3);
    const int swK = (lane & 7) ^ (srow & 7);
    const unsigned short* Kg = qkv + 2048 + kvh * 64 + swK * 8;  // + (kbase+srow+32i)*3072
    unsigned short* Ksl = Ks + wave * 512;
    // V staging map (128-u16 rows, 16 chunk slots)
    const int vrow = wave * 4 + (lane >> 4);
    const int swV = (lane & 15) ^ (vrow & 7);
    const unsigned short* Vg = vt + (size_t)(kvh * 64 + vrow) * 2048 + swV * 8;  // + 16i*2048 + kbase
    unsigned short* Vsl = Vs + wave * 512;

    // Q fragments (MFMA B-operand: n=q=l15, k=quad*8+j), pre-scaled by 1/8
    bf16x8 qf[2][2];
#pragma unroll
    for (int mt = 0; mt < 2; mt++)
#pragma unroll
        for (int ks = 0; ks < 2; ks++) {
            u32x4 raw = *(const u32x4*)&qkv[(size_t)(w0 + 16 * mt + l15) * 3072 + h * 64 + quad * 8 + 32 * ks];
            u16x8 t = __builtin_bit_cast(u16x8, raw);
#pragma unroll
            for (int j = 0; j < 8; j++) t[j] = f2bf(bf2f(t[j]) * 0.125f);
            qf[mt][ks] = __builtin_bit_cast(bf16x8, t);
        }

    bf16x8 ones;
#pragma unroll
    for (int j = 0; j < 8; j++) ones[j] = (__bf16)1.0f;

    f32x4 acc_o[2][4] = {};
    f32x4 acc_l[2] = {};

    const float LOG2E = 1.44269504088896f;
    const float MB = -17.3123404906676f;  // -12 * log2e

    for (int kb2 = 0; kb2 < 16; kb2++) {
        const int kbase = kb2 * 128;
#pragma unroll
        for (int i = 0; i < 4; i++) {
            glds16(Kg + (size_t)(kbase + srow + 32 * i) * 3072, Ksl + i * 2048);
            glds16(Vg + (size_t)(16 * i) * 2048 + kbase, Vsl + i * 2048);
        }
        __syncthreads();

#pragma unroll
        for (int kh = 0; kh < 2; kh++) {
            // S^T = K Q^T : A = K-frag (m=kv), B = Q-frag (n=q)
            f32x4 st[2][4] = {};
#pragma unroll
            for (int n = 0; n < 4; n++) {
                const int row = kh * 64 + 16 * n + l15;
                const bf16x8 kf0 = __builtin_bit_cast(bf16x8,
                    *(const u32x4*)&Ks[row * 64 + ((quad ^ (l15 & 7)) * 8)]);
                const bf16x8 kf1 = __builtin_bit_cast(bf16x8,
                    *(const u32x4*)&Ks[row * 64 + (((quad + 4) ^ (l15 & 7)) * 8)]);
#pragma unroll
                for (int mt = 0; mt < 2; mt++) {
                    st[mt][n] = MFMA16(kf0, qf[mt][0], st[mt][n]);
                    st[mt][n] = MFMA16(kf1, qf[mt][1], st[mt][n]);
                }
            }

            // p = exp2(s*log2e - 12*log2e); lane holds q=l15, kv=16n+quad*4+r
            // -> contiguous b64 store into Sw[q][kv]
#pragma unroll
            for (int mt = 0; mt < 2; mt++)
#pragma unroll
                for (int n = 0; n < 4; n++) {
                    u16x4 pk;
#pragma unroll
                    for (int r = 0; r < 4; r++)
                        pk[r] = f2bf(exp2f(fmaf(st[mt][n][r], LOG2E, MB)));
                    *(u16x4*)&Sw[16 * mt + l15][16 * n + quad * 4] = pk;
                }

            // P A-frags (m=q=l15, k=kv=quad*8+j) straight from Sw rows
            bf16x8 pf[2][2];
#pragma unroll
            for (int mt = 0; mt < 2; mt++) {
                pf[mt][0] = __builtin_bit_cast(bf16x8, *(const u32x4*)&Sw[16 * mt + l15][quad * 8]);
                pf[mt][1] = __builtin_bit_cast(bf16x8, *(const u32x4*)&Sw[16 * mt + l15][quad * 8 + 32]);
            }

            // row sums: acc_l[mt] += P @ ones  (C-rows match acc_o's rows)
#pragma unroll
            for (int mt = 0; mt < 2; mt++) {
                acc_l[mt] = MFMA16(pf[mt][0], ones, acc_l[mt]);
                acc_l[mt] = MFMA16(pf[mt][1], ones, acc_l[mt]);
            }

            // O += P @ V : B = V^T rows (n=d=l15, k=kv)
#pragma unroll
            for (int nt = 0; nt < 4; nt++) {
                const int row = 16 * nt + l15;
                const int c0 = kh * 8 + (quad ^ (l15 & 7));
                const int c1 = kh * 8 + ((quad + 4) ^ (l15 & 7));
                const bf16x8 vf0 = __builtin_bit_cast(bf16x8, *(const u32x4*)&Vs[row * 128 + c0 * 8]);
                const bf16x8 vf1 = __builtin_bit_cast(bf16x8, *(const u32x4*)&Vs[row * 128 + c1 * 8]);
#pragma unroll
                for (int mt = 0; mt < 2; mt++) {
                    acc_o[mt][nt] = MFMA16(pf[mt][0], vf0, acc_o[mt][nt]);
                    acc_o[mt][nt] = MFMA16(pf[mt][1], vf1, acc_o[mt][nt]);
                }
            }
        }
        __syncthreads();
    }

    // epilogue: acc_o and acc_l share lane layout q=quad*4+r (+16mt), d=16nt+l15
#pragma unroll
    for (int mt = 0; mt < 2; mt++) {
        float linv[4];
#pragma unroll
        for (int r = 0; r < 4; r++) linv[r] = 1.0f / acc_l[mt][r];
#pragma unroll
        for (int nt = 0; nt < 4; nt++)
#pragma unroll
            for (int r = 0; r < 4; r++)
                attn_out[(size_t)(w0 + 16 * mt + quad * 4 + r) * 2048 + h * 64 + 16 * nt + l15] =
                    f2bf(acc_o[mt][nt][r] * linv[r]);
    }
}

// ---------------------------------------------------------------------------
extern "C" void kernel_launch(void* const* d_in, const int* in_sizes, int n_in,
                              void* d_out, int out_size, void* d_ws, size_t ws_size,
                              hipStream_t stream) {
    (void)in_sizes; (void)n_in; (void)out_size; (void)ws_size;

    const float* X  = (const float*)d_in[0];
    const float* Wq = (const float*)d_in[1];
    const float* Wk = (const float*)d_in[2];
    const float* Wv = (const float*)d_in[3];
    const float* Wo = (const float*)d_in[4];

    // ws (u16): phase1 Xbf[0..4.19M) wqkvT[4.19M..10.49M)
    //           phase2 vt[0..1.05M) attnO[1.05M..5.24M) woT[5.24M..9.44M)
    // qkv parks in d_out (12.6MB of 16.8MB); final GEMM rewrites d_out in f32.
    unsigned short* ws16  = (unsigned short*)d_ws;
    unsigned short* Xbf   = ws16;
    unsigned short* wqkvT = ws16 + (size_t)4194304;
    unsigned short* qkv   = (unsigned short*)d_out;
    unsigned short* vt    = ws16;
    unsigned short* attnO = ws16 + (size_t)1048576;
    unsigned short* woT   = ws16 + (size_t)5242880;

    // X cvt + Wqkv transpose
    prep1<<<10240, 256, 0, stream>>>(X, Wq, Wk, Wv, Xbf, wqkvT);

    // QKV = X @ [Wq|Wk|Wv] -> bf16 in d_out, RoPE fused in epilogue
    gemm_bt<64, true><<<dim3(32, 24), 256, 0, stream>>>(Xbf, wqkvT, qkv, 2048, 2048, 2048, 3072, 0);

    // Wo transpose (into dead wqkvT region) + V^T (into dead Xbf region)
    prep2<<<5120, 256, 0, stream>>>(Wo, qkv, woT, vt);

    // attention -> attnO (bf16)
    attn_kernel<<<dim3(16, 32), 256, 0, stream>>>(qkv, vt, attnO);

    // out = attnO @ Wo -> f32 into d_out (overwrites dead qkv)
    gemm_bt<64, false><<<dim3(32, 16), 256, 0, stream>>>(attnO, woT, (void*)d_out, 2048, 2048, 2048, 2048, 1);
}